// Round 6
// baseline (455.156 us; speedup 1.0000x reference)
//
#include <hip/hip_runtime.h>
#include <hip/hip_bf16.h>
#include <stdint.h>

// ---------------------------------------------------------------------------
// Fused attention block, bf16 MFMA pipeline:
//   cvt(x) / transpose(w_qkv,w_out) -> GEMM qkv (R4 gemm8p: fine-interleaved
//   phases, 3-slot ring, T2 swizzle, counted vmcnt, T5) -> rmsnorm+rope
//   -> transpose V -> flash attention (KVBLK=128, V direct-global, no V LDS)
//   -> GEMM out-proj (+bias, fp32)
// ---------------------------------------------------------------------------

typedef unsigned short ushort8 __attribute__((ext_vector_type(8)));
typedef short          bf16x8 __attribute__((ext_vector_type(8)));
typedef float          f32x4  __attribute__((ext_vector_type(4)));

#define B_   2
#define L_   2048
#define DM   2048
#define NH   16
#define HD   128
#define QKVW 6144   // 3*DM

__device__ __forceinline__ uint16_t f2bf(float f){
  uint32_t u = __builtin_bit_cast(uint32_t, f);
  u += 0x7FFFu + ((u >> 16) & 1u);          // RNE
  return (uint16_t)(u >> 16);
}
__device__ __forceinline__ float bf2f(uint16_t h){
  uint32_t u = ((uint32_t)h) << 16;
  return __builtin_bit_cast(float, u);
}

// async global->LDS, 16B per lane; LDS dest is wave-uniform base + lane*16
#define GLD16(gp, lp) __builtin_amdgcn_global_load_lds( \
  (const __attribute__((address_space(1))) void*)(gp),  \
  (__attribute__((address_space(3))) void*)(lp), 16, 0, 0)

// ---------------- rope cos/sin table: [2048][64] each --------------------
__global__ __launch_bounds__(256) void rope_table(float* __restrict__ ct, float* __restrict__ st){
  int i = blockIdx.x * 256 + threadIdx.x;   // 131072 threads
  int t = i >> 6, d = i & 63;
  float invf = powf(10000.f, -(float)d * (1.f/64.f));
  float s, c;
  sincosf((float)t * invf, &s, &c);
  ct[i] = c; st[i] = s;
}

// ---------------- fp32 -> bf16 convert (x) -------------------------------
__global__ __launch_bounds__(256) void cvt_f32_bf16(const float* __restrict__ x,
                                                    uint16_t* __restrict__ o, int n8){
  int i = blockIdx.x * 256 + threadIdx.x;
  if (i < n8){
    const float4* xv = (const float4*)x;
    float4 a = xv[(size_t)i*2], b = xv[(size_t)i*2+1];
    ushort8 v;
    v[0]=f2bf(a.x); v[1]=f2bf(a.y); v[2]=f2bf(a.z); v[3]=f2bf(a.w);
    v[4]=f2bf(b.x); v[5]=f2bf(b.y); v[6]=f2bf(b.z); v[7]=f2bf(b.w);
    *(ushort8*)(o + (size_t)i*8) = v;
  }
}

// ---------------- W [R][C] fp32 -> Wt [C][R] bf16 ------------------------
__global__ __launch_bounds__(256) void transpose_w(const float* __restrict__ W,
                                                   uint16_t* __restrict__ Wt, int R, int C){
  __shared__ float T[64][65];
  const int rb = blockIdx.x, cb = blockIdx.y;
  const int tid = threadIdx.x;
#pragma unroll
  for (int i=0;i<4;i++){
    int rr = i*16 + (tid >> 4);
    int cc = (tid & 15) * 4;
    float4 v = *(const float4*)(W + (size_t)(rb*64 + rr) * C + cb*64 + cc);
    T[rr][cc] = v.x; T[rr][cc+1] = v.y; T[rr][cc+2] = v.z; T[rr][cc+3] = v.w;
  }
  __syncthreads();
  const int oc = tid >> 2, rc = (tid & 3) * 16;
  ushort8 o0, o1;
#pragma unroll
  for (int j=0;j<8;j++){ o0[j] = f2bf(T[rc+j][oc]); o1[j] = f2bf(T[rc+8+j][oc]); }
  size_t ob = (size_t)(cb*64 + oc) * R + rb*64 + rc;
  *(ushort8*)(Wt + ob)     = o0;
  *(ushort8*)(Wt + ob + 8) = o1;
}

// ---------------- GEMM: C[M][N] = A[M][K] * Bt[N][K]^T + bias ------------
// R4 structure (measured 793 TF): BM=256, BN=128, BK=64, 8 waves (2Mx4N),
// 3-slot LDS ring, prefetch distance 2, staging split 3+3 across the two
// 16-MFMA phases, counted vmcnt(6), T2 XOR-swizzle (0 conflicts), T5 setprio.
// Grids chosen as exact multiples of 256 CUs (full rounds at 1 block/CU).
template<int OUTB>
__global__ __launch_bounds__(512, 2) void gemm8p(
    const uint16_t* __restrict__ A, const uint16_t* __restrict__ Bt,
    const float* __restrict__ bias, void* __restrict__ Cv,
    int M, int N, int K, int nbn)
{
  __shared__ uint16_t LA[3*16384];   // 3 x [256][64]
  __shared__ uint16_t LB[3*8192];    // 3 x [128][64]
  const int nwg = (M >> 8) * nbn;
  const int q8  = nwg >> 3;
  const int id  = ((int)blockIdx.x & 7) * q8 + ((int)blockIdx.x >> 3);
  const int bm = id / nbn, bn = id % nbn;
  const int tid = threadIdx.x;
  const int lane = tid & 63, w = tid >> 6;
  const int wm = w >> 2, wn = w & 3;
  const int l15 = lane & 15, lh = lane >> 4;
  const int NT = K >> 6;

  // staging: per-lane inverse-swizzled global source column
  const int qs3 = ((lane & 7) ^ ((lane >> 3) & 7)) * 8;
  const uint16_t* gA_ = A  + (size_t)((bm << 8) + (w << 5) + (lane >> 3)) * K + qs3;
  const uint16_t* gB_ = Bt + (size_t)((bn << 7) + (w << 4) + (lane >> 3)) * K + qs3;
  uint16_t* lA_ = LA + (w << 11);    // wave-uniform LDS bases
  uint16_t* lB_ = LB + (w << 10);

  // fragment-read swizzled offsets (elements)
  const int sw0 = ((lh       ^ (l15 & 7)) << 3);   // kc=0
  const int sw1 = (((4 | lh) ^ (l15 & 7)) << 3);   // kc=1
  const int aoff = (((wm << 7) + l15) << 6);
  const int boff = (((wn << 5) + l15) << 6);

  f32x4 acc[8][2];
#pragma unroll
  for (int i=0;i<8;i++){
    acc[i][0] = f32x4{0.f,0.f,0.f,0.f};
    acc[i][1] = f32x4{0.f,0.f,0.f,0.f};
  }

  auto STAGE_A = [&](int tt, int s, int i){
    GLD16(gA_ + (size_t)tt*64 + (size_t)(i*8)*K, lA_ + s*16384 + i*512);
  };
  auto STAGE_B = [&](int tt, int s, int i){
    GLD16(gB_ + (size_t)tt*64 + (size_t)(i*8)*K, lB_ + s*8192 + i*512);
  };

  // prologue: stage tiles 0,1; wait tile 0 (6 of 12 outstanding = tile 1)
#pragma unroll
  for (int i=0;i<4;i++) STAGE_A(0, 0, i);
#pragma unroll
  for (int i=0;i<2;i++) STAGE_B(0, 0, i);
#pragma unroll
  for (int i=0;i<4;i++) STAGE_A(1, 1, i);
#pragma unroll
  for (int i=0;i<2;i++) STAGE_B(1, 1, i);
  asm volatile("s_waitcnt vmcnt(6)" ::: "memory");
  __builtin_amdgcn_s_barrier();

  int sl = 0, sl2 = 2;
  for (int t = 0; t < NT; ++t){
    const bool pf = (t + 2 < NT);
    const uint16_t* la = LA + sl*16384;
    const uint16_t* lb = LB + sl*8192;

    // ---- phase 0 (kc=0): 10 ds_read || 3 G-loads || 16 MFMA ----
    {
      bf16x8 af[8], bfr[2];
#pragma unroll
      for (int mi=0;mi<8;mi++) af[mi] = *(const bf16x8*)(la + aoff + mi*1024 + sw0);
#pragma unroll
      for (int ni=0;ni<2;ni++) bfr[ni] = *(const bf16x8*)(lb + boff + ni*1024 + sw0);
      if (pf){ STAGE_A(t+2, sl2, 0); STAGE_A(t+2, sl2, 1); STAGE_A(t+2, sl2, 2); }
      __builtin_amdgcn_s_barrier();
      __builtin_amdgcn_s_setprio(1);
#pragma unroll
      for (int mi=0;mi<8;mi++)
#pragma unroll
        for (int ni=0;ni<2;ni++)
          acc[mi][ni] = __builtin_amdgcn_mfma_f32_16x16x32_bf16(af[mi], bfr[ni], acc[mi][ni], 0, 0, 0);
      __builtin_amdgcn_s_setprio(0);
      __builtin_amdgcn_s_barrier();
    }
    // ---- phase 1 (kc=1): 10 ds_read || 3 G-loads || 16 MFMA ----
    {
      bf16x8 af[8], bfr[2];
#pragma unroll
      for (int mi=0;mi<8;mi++) af[mi] = *(const bf16x8*)(la + aoff + mi*1024 + sw1);
#pragma unroll
      for (int ni=0;ni<2;ni++) bfr[ni] = *(const bf16x8*)(lb + boff + ni*1024 + sw1);
      if (pf){ STAGE_A(t+2, sl2, 3); STAGE_B(t+2, sl2, 0); STAGE_B(t+2, sl2, 1); }
      __builtin_amdgcn_s_barrier();
      __builtin_amdgcn_s_setprio(1);
#pragma unroll
      for (int mi=0;mi<8;mi++)
#pragma unroll
        for (int ni=0;ni<2;ni++)
          acc[mi][ni] = __builtin_amdgcn_mfma_f32_16x16x32_bf16(af[mi], bfr[ni], acc[mi][ni], 0, 0, 0);
      __builtin_amdgcn_s_setprio(0);
    }
    // ---- boundary: counted vmcnt (tile t+1 landed; t+2 may be in flight) ----
    if (t < NT-2)       { asm volatile("s_waitcnt vmcnt(6)" ::: "memory"); }
    else if (t == NT-2) { asm volatile("s_waitcnt vmcnt(0)" ::: "memory"); }
    if (t < NT-1) __builtin_amdgcn_s_barrier();
    sl  = (sl  == 2) ? 0 : sl  + 1;
    sl2 = (sl2 == 2) ? 0 : sl2 + 1;
  }

  // ---- epilogue ----
  const int cm = (bm << 8) + (wm << 7);
  const int cn = (bn << 7) + (wn << 5);
#pragma unroll
  for (int ni=0;ni<2;ni++){
    int col = cn + ni*16 + l15;
    float bs = bias[col];
#pragma unroll
    for (int mi=0;mi<8;mi++){
#pragma unroll
      for (int r=0;r<4;r++){
        int rowg = cm + mi*16 + lh*4 + r;        // C/D: col=lane&15, row=(lane>>4)*4+r
        float v = acc[mi][ni][r] + bs;
        if (OUTB) ((uint16_t*)Cv)[(size_t)rowg * N + col] = f2bf(v);
        else      ((float*)Cv)[(size_t)rowg * N + col] = v;
      }
    }
  }
}

// ---------------- RMSNorm + RoPE in place on q,k parts of qkv ------------
__global__ __launch_bounds__(256) void rmsrope(
    uint16_t* __restrict__ qkv, const float* __restrict__ qs, const float* __restrict__ ks,
    const float* __restrict__ ct, const float* __restrict__ st)
{
  const int bx  = blockIdx.x;          // token index b*2048+t
  const int t   = bx & (L_-1);
  const int tid = threadIdx.x;
  const int h   = tid >> 4;
  const int dq  = (tid & 15) * 8;
  const int dd  = dq & 63;
  const bool hi = dq >= 64;
  const size_t base = (size_t)bx * QKVW;
  float cs[8], sn[8];
#pragma unroll
  for (int j=0;j<8;j++){ cs[j] = ct[(size_t)t*64 + dd + j]; sn[j] = st[(size_t)t*64 + dd + j]; }
#pragma unroll
  for (int qk = 0; qk < 2; qk++){
    uint16_t* p = qkv + base + qk*DM + h*HD + dq;
    ushort8 vv = *(const ushort8*)p;
    float x[8]; float ssum = 0.f;
#pragma unroll
    for (int j=0;j<8;j++){ x[j] = bf2f(vv[j]); ssum += x[j]*x[j]; }
    ssum += __shfl_xor(ssum, 1); ssum += __shfl_xor(ssum, 2);
    ssum += __shfl_xor(ssum, 4); ssum += __shfl_xor(ssum, 8);
    const float inv = rsqrtf(ssum * (1.f/128.f) + 1e-6f);
    const float* sc = qk ? ks : qs;
    float y[8];
#pragma unroll
    for (int j=0;j<8;j++) y[j] = x[j] * inv * sc[dq + j];
    float z[8];                       // partner half (d +/- 64) via lane^8
#pragma unroll
    for (int j=0;j<8;j++) z[j] = __shfl_xor(y[j], 8);
    ushort8 o;
#pragma unroll
    for (int j=0;j<8;j++){
      float r = hi ? (z[j]*sn[j] + y[j]*cs[j])
                   : (y[j]*cs[j] - z[j]*sn[j]);
      o[j] = f2bf(r);
    }
    *(ushort8*)p = o;
  }
}

// ---------------- V [b][t][h][d] -> VT [b,h][d][t] -----------------------
__global__ __launch_bounds__(256) void transpose_v(const uint16_t* __restrict__ qkv,
                                                   uint16_t* __restrict__ vt){
  __shared__ uint16_t T[64][136];
  const int tb = blockIdx.x, bh = blockIdx.y;
  const int b = bh >> 4, h = bh & 15;
  const int tid = threadIdx.x;
#pragma unroll
  for (int i=0;i<4;i++){
    int g = i*256 + tid, tt = g >> 4, c = g & 15;
    *(ushort8*)(&T[tt][c*8]) =
      *(const ushort8*)(qkv + ((size_t)b*L_ + tb*64 + tt)*QKVW + 2*DM + h*HD + c*8);
  }
  __syncthreads();
  const int d = tid >> 1, th = tid & 1;
#pragma unroll
  for (int i=0;i<4;i++){
    ushort8 o;
#pragma unroll
    for (int j=0;j<8;j++) o[j] = T[th*32 + i*8 + j][d];
    *(ushort8*)(vt + ((size_t)bh*HD + d)*L_ + tb*64 + th*32 + i*8) = o;
  }
}

// ---------------- flash attention (causal, balanced pairs) ---------------
// grid (qp=16, bh=32); block handles q-tiles {qp, 31-qp}; KVBLK=128 ->
// (qp>>1)+1 + ((31-qp)>>1)+1 = 17 K-tile iterations per block, uniform.
// 4 waves x 16 q-rows (QBLK=64). Q in registers; K staged in padded LDS
// (reg-prefetched); V fragments read DIRECTLY from global vt[bh][d][L]
// (B-fragment layout; L1/L2-resident - staging was pure overhead, m169).
// LDS 52 KB -> 2 blocks/CU. T5 setprio around MFMA clusters.
__global__ __launch_bounds__(256) void flash_attn(
    const uint16_t* __restrict__ qkv, const uint16_t* __restrict__ vt,
    uint16_t* __restrict__ ao)
{
  const int qp = blockIdx.x;
  const int bh = blockIdx.y;
  const int b = bh >> 4, h = bh & 15;
  const int tid = threadIdx.x;
  const int lane = tid & 63, w = tid >> 6;
  const int l15 = lane & 15, lh = lane >> 4;

  __shared__ uint16_t Ks[128][136];
  __shared__ uint16_t Ps[4][16][136];

  const float SCL = 0.12751744f;      // (1/sqrt(128)) * log2(e)
  const uint16_t* vtb = vt + (size_t)bh * HD * L_;

  for (int sel = 0; sel < 2; sel++){
    const int qb = sel ? (31 - qp) : qp;

    // Q fragments: wave w owns q rows qb*64 + w*16 + (0..15)
    const size_t qrow = (size_t)b * L_ + qb*64 + w*16 + l15;
    const uint16_t* qp_ = qkv + qrow * QKVW + h * HD;
    bf16x8 qf[4];
#pragma unroll
    for (int c = 0; c < 4; c++) qf[c] = *(const bf16x8*)(qp_ + c*32 + lh*8);

    float m_r[4], l_r[4];
    f32x4 oacc[8];
#pragma unroll
    for (int r = 0; r < 4; r++){ m_r[r] = -3.0e38f; l_r[r] = 0.f; }
#pragma unroll
    for (int nt = 0; nt < 8; nt++) oacc[nt] = f32x4{0.f,0.f,0.f,0.f};

    const int ntile = (qb >> 1) + 1;     // ceil((qb+1)*64 / 128)
    ushort8 rk[8];

    // prologue: K tile 0 into regs (128 rows x 128 cols)
#pragma unroll
    for (int i = 0; i < 8; i++){
      int g = i*256 + tid, row = g >> 4, c = g & 15;
      rk[i] = *(const ushort8*)(qkv + ((size_t)b*L_ + row)*QKVW + DM + h*HD + c*8);
    }

    for (int kt = 0; kt < ntile; kt++){
      __syncthreads();                  // prior tile's Ks reads complete
#pragma unroll
      for (int i = 0; i < 8; i++){ int g = i*256+tid; *(ushort8*)(&Ks[g>>4][(g&15)*8]) = rk[i]; }
      __syncthreads();

      // prefetch next K tile into regs; latency hides under compute
      if (kt + 1 < ntile){
        const int k2 = (kt + 1) * 128;
#pragma unroll
        for (int i = 0; i < 8; i++){
          int g = i*256 + tid, row = g >> 4, c = g & 15;
          rk[i] = *(const ushort8*)(qkv + ((size_t)b*L_ + k2 + row)*QKVW + DM + h*HD + c*8);
        }
      }

      // ---- S = Q K^T  (16q x 128k) ----
      f32x4 s[8];
#pragma unroll
      for (int nt = 0; nt < 8; nt++) s[nt] = f32x4{0.f,0.f,0.f,0.f};
      __builtin_amdgcn_s_setprio(1);
#pragma unroll
      for (int c = 0; c < 4; c++){
#pragma unroll
        for (int nt = 0; nt < 8; nt++){
          bf16x8 kf = *(const bf16x8*)(&Ks[nt*16 + l15][c*32 + lh*8]);
          s[nt] = __builtin_amdgcn_mfma_f32_16x16x32_bf16(qf[c], kf, s[nt], 0, 0, 0);
        }
      }
      __builtin_amdgcn_s_setprio(0);

      // ---- scale + causal mask (log2 domain); only edge tile masks ----
      const bool edge = (kt == ntile - 1);
      const int qrg = qb*64 + w*16 + lh*4;          // this lane's q rows base
#pragma unroll
      for (int nt = 0; nt < 8; nt++){
        int kcol = kt*128 + nt*16 + l15;
#pragma unroll
        for (int r = 0; r < 4; r++){
          float v = s[nt][r] * SCL;
          if (edge && (kcol > qrg + r)) v = -1.0e30f;
          s[nt][r] = v;
        }
      }
      // ---- online softmax (per q-row; 16-lane groups share a row) ----
      float alpha[4];
#pragma unroll
      for (int r = 0; r < 4; r++){
        float v = s[0][r];
#pragma unroll
        for (int nt = 1; nt < 8; nt++) v = fmaxf(v, s[nt][r]);
        v = fmaxf(v, __shfl_xor(v, 1));
        v = fmaxf(v, __shfl_xor(v, 2));
        v = fmaxf(v, __shfl_xor(v, 4));
        v = fmaxf(v, __shfl_xor(v, 8));
        float mn = fmaxf(m_r[r], v);
        float al = exp2f(m_r[r] - mn);
        m_r[r] = mn; alpha[r] = al;
        float rs = 0.f;
#pragma unroll
        for (int nt = 0; nt < 8; nt++){
          float p = exp2f(s[nt][r] - mn);
          rs += p;
          Ps[w][lh*4 + r][nt*16 + l15] = f2bf(p);
        }
        rs += __shfl_xor(rs, 1);
        rs += __shfl_xor(rs, 2);
        rs += __shfl_xor(rs, 4);
        rs += __shfl_xor(rs, 8);
        l_r[r] = l_r[r] * al + rs;
      }
#pragma unroll
      for (int nt = 0; nt < 8; nt++)
#pragma unroll
        for (int r = 0; r < 4; r++) oacc[nt][r] *= alpha[r];

      asm volatile("s_waitcnt lgkmcnt(0)" ::: "memory");   // Ps writes visible (wave-private)
      // ---- O += P V : A=P[16q][128k] from LDS, B=V[128k][16d] direct global ----
      const uint16_t* vkt = vtb + kt*128;
      __builtin_amdgcn_s_setprio(1);
#pragma unroll
      for (int kc = 0; kc < 4; kc++){
        bf16x8 pf = *(const bf16x8*)(&Ps[w][l15][kc*32 + lh*8]);
#pragma unroll
        for (int nt = 0; nt < 8; nt++){
          bf16x8 vf = *(const bf16x8*)(vkt + (size_t)(nt*16 + l15)*L_ + kc*32 + lh*8);
          oacc[nt] = __builtin_amdgcn_mfma_f32_16x16x32_bf16(pf, vf, oacc[nt], 0, 0, 0);
        }
      }
      __builtin_amdgcn_s_setprio(0);
    }
    // ---- epilogue: O /= l, write [token][h*128+d] ----
    float invl[4];
#pragma unroll
    for (int r = 0; r < 4; r++) invl[r] = 1.f / l_r[r];
#pragma unroll
    for (int nt = 0; nt < 8; nt++){
#pragma unroll
      for (int r = 0; r < 4; r++){
        float v = oacc[nt][r] * invl[r];
        size_t row = (size_t)b*L_ + qb*64 + w*16 + lh*4 + r;
        ao[row * DM + h*HD + nt*16 + l15] = f2bf(v);
      }
    }
  }
}

// ---------------------------------------------------------------------------
extern "C" void kernel_launch(void* const* d_in, const int* in_sizes, int n_in,
                              void* d_out, int out_size, void* d_ws, size_t ws_size,
                              hipStream_t stream)
{
  (void)in_sizes; (void)n_in; (void)out_size; (void)ws_size;
  const float* x       = (const float*)d_in[0];
  const float* w_qkv   = (const float*)d_in[1];
  const float* b_qkv   = (const float*)d_in[2];
  const float* q_scale = (const float*)d_in[3];
  const float* k_scale = (const float*)d_in[4];
  const float* w_out   = (const float*)d_in[5];
  const float* b_out   = (const float*)d_in[6];
  float* out = (float*)d_out;

  // workspace layout (~102 MB), with lifetime-based reuse
  char* ws = (char*)d_ws;
  uint16_t* qkv   = (uint16_t*)(ws);                                   // 50,331,648 B
  uint16_t* reg1  = (uint16_t*)(ws + 50331648);                        // 16,777,216 B
  uint16_t* reg2  = (uint16_t*)(ws + 50331648 + 16777216);             // 25,165,824 B
  uint16_t* woutT = (uint16_t*)(ws + 50331648 + 16777216 + 25165824);  //  8,388,608 B
  float*    ct    = (float*)(ws + 100663296);                          //    524,288 B
  float*    st    = ct + 131072;                                       //    524,288 B

  uint16_t* xb    = reg1;   // x bf16 [4096][2048]   (dead after gemm_qkv)
  uint16_t* ao    = reg1;   // attn out bf16 [4096][2048]
  uint16_t* wqkvT = reg2;   // [6144][2048]          (dead after gemm_qkv)
  uint16_t* vt    = reg2;   // [32][128][2048]

  rope_table  <<<512, 256, 0, stream>>>(ct, st);
  cvt_f32_bf16<<<4096, 256, 0, stream>>>(x, xb, 1048576);
  transpose_w <<<dim3(32, 96), 256, 0, stream>>>(w_qkv, wqkvT, 2048, 6144);
  transpose_w <<<dim3(32, 32), 256, 0, stream>>>(w_out, woutT, 2048, 2048);
  gemm8p<1>   <<<768, 512, 0, stream>>>(xb, wqkvT, b_qkv, qkv, 4096, 6144, 2048, 48);
  rmsrope     <<<4096, 256, 0, stream>>>(qkv, q_scale, k_scale, ct, st);
  transpose_v <<<dim3(32, 32), 256, 0, stream>>>(qkv, vt);
  flash_attn  <<<dim3(16, 32), 256, 0, stream>>>(qkv, vt, ao);
  gemm8p<0>   <<<256, 512, 0, stream>>>(ao, woutT, b_out, out, 4096, 2048, 2048, 16);
}

// Round 7
// 314.113 us; speedup vs baseline: 1.4490x; 1.4490x over previous
//
#include <hip/hip_runtime.h>
#include <hip/hip_bf16.h>
#include <stdint.h>

// ---------------------------------------------------------------------------
// Fused attention block, bf16 MFMA pipeline:
//   cvt(x) / transpose(w_qkv,w_out) -> GEMM qkv (R4 gemm8p: fine-interleaved
//   phases, 3-slot ring, T2 swizzle, counted vmcnt, T5) -> rmsnorm+rope
//   -> transpose V -> flash attention (R4 structure + T5 setprio + T13
//   defer-max) -> GEMM out-proj (+bias, fp32)
// ---------------------------------------------------------------------------

typedef unsigned short ushort8 __attribute__((ext_vector_type(8)));
typedef short          bf16x8 __attribute__((ext_vector_type(8)));
typedef float          f32x4  __attribute__((ext_vector_type(4)));

#define B_   2
#define L_   2048
#define DM   2048
#define NH   16
#define HD   128
#define QKVW 6144   // 3*DM

__device__ __forceinline__ uint16_t f2bf(float f){
  uint32_t u = __builtin_bit_cast(uint32_t, f);
  u += 0x7FFFu + ((u >> 16) & 1u);          // RNE
  return (uint16_t)(u >> 16);
}
__device__ __forceinline__ float bf2f(uint16_t h){
  uint32_t u = ((uint32_t)h) << 16;
  return __builtin_bit_cast(float, u);
}

// async global->LDS, 16B per lane; LDS dest is wave-uniform base + lane*16
#define GLD16(gp, lp) __builtin_amdgcn_global_load_lds( \
  (const __attribute__((address_space(1))) void*)(gp),  \
  (__attribute__((address_space(3))) void*)(lp), 16, 0, 0)

// ---------------- rope cos/sin table: [2048][64] each --------------------
__global__ __launch_bounds__(256) void rope_table(float* __restrict__ ct, float* __restrict__ st){
  int i = blockIdx.x * 256 + threadIdx.x;   // 131072 threads
  int t = i >> 6, d = i & 63;
  float invf = powf(10000.f, -(float)d * (1.f/64.f));
  float s, c;
  sincosf((float)t * invf, &s, &c);
  ct[i] = c; st[i] = s;
}

// ---------------- fp32 -> bf16 convert (x) -------------------------------
__global__ __launch_bounds__(256) void cvt_f32_bf16(const float* __restrict__ x,
                                                    uint16_t* __restrict__ o, int n8){
  int i = blockIdx.x * 256 + threadIdx.x;
  if (i < n8){
    const float4* xv = (const float4*)x;
    float4 a = xv[(size_t)i*2], b = xv[(size_t)i*2+1];
    ushort8 v;
    v[0]=f2bf(a.x); v[1]=f2bf(a.y); v[2]=f2bf(a.z); v[3]=f2bf(a.w);
    v[4]=f2bf(b.x); v[5]=f2bf(b.y); v[6]=f2bf(b.z); v[7]=f2bf(b.w);
    *(ushort8*)(o + (size_t)i*8) = v;
  }
}

// ---------------- W [R][C] fp32 -> Wt [C][R] bf16 ------------------------
__global__ __launch_bounds__(256) void transpose_w(const float* __restrict__ W,
                                                   uint16_t* __restrict__ Wt, int R, int C){
  __shared__ float T[64][65];
  const int rb = blockIdx.x, cb = blockIdx.y;
  const int tid = threadIdx.x;
#pragma unroll
  for (int i=0;i<4;i++){
    int rr = i*16 + (tid >> 4);
    int cc = (tid & 15) * 4;
    float4 v = *(const float4*)(W + (size_t)(rb*64 + rr) * C + cb*64 + cc);
    T[rr][cc] = v.x; T[rr][cc+1] = v.y; T[rr][cc+2] = v.z; T[rr][cc+3] = v.w;
  }
  __syncthreads();
  const int oc = tid >> 2, rc = (tid & 3) * 16;
  ushort8 o0, o1;
#pragma unroll
  for (int j=0;j<8;j++){ o0[j] = f2bf(T[rc+j][oc]); o1[j] = f2bf(T[rc+8+j][oc]); }
  size_t ob = (size_t)(cb*64 + oc) * R + rb*64 + rc;
  *(ushort8*)(Wt + ob)     = o0;
  *(ushort8*)(Wt + ob + 8) = o1;
}

// ---------------- GEMM: C[M][N] = A[M][K] * Bt[N][K]^T + bias ------------
// R4 structure (measured ~793 TF): BM=256, BN=128, BK=64, 8 waves (2Mx4N),
// 3-slot LDS ring, prefetch distance 2, staging split 3+3 across the two
// 16-MFMA phases, counted vmcnt(6), T2 XOR-swizzle (0 conflicts), T5 setprio.
// Grids are exact multiples of 256 CUs (full rounds at 1 block/CU).
template<int OUTB>
__global__ __launch_bounds__(512, 2) void gemm8p(
    const uint16_t* __restrict__ A, const uint16_t* __restrict__ Bt,
    const float* __restrict__ bias, void* __restrict__ Cv,
    int M, int N, int K, int nbn)
{
  __shared__ uint16_t LA[3*16384];   // 3 x [256][64]
  __shared__ uint16_t LB[3*8192];    // 3 x [128][64]
  const int nwg = (M >> 8) * nbn;
  const int q8  = nwg >> 3;
  const int id  = ((int)blockIdx.x & 7) * q8 + ((int)blockIdx.x >> 3);
  const int bm = id / nbn, bn = id % nbn;
  const int tid = threadIdx.x;
  const int lane = tid & 63, w = tid >> 6;
  const int wm = w >> 2, wn = w & 3;
  const int l15 = lane & 15, lh = lane >> 4;
  const int NT = K >> 6;

  // staging: per-lane inverse-swizzled global source column
  const int qs3 = ((lane & 7) ^ ((lane >> 3) & 7)) * 8;
  const uint16_t* gA_ = A  + (size_t)((bm << 8) + (w << 5) + (lane >> 3)) * K + qs3;
  const uint16_t* gB_ = Bt + (size_t)((bn << 7) + (w << 4) + (lane >> 3)) * K + qs3;
  uint16_t* lA_ = LA + (w << 11);    // wave-uniform LDS bases
  uint16_t* lB_ = LB + (w << 10);

  // fragment-read swizzled offsets (elements)
  const int sw0 = ((lh       ^ (l15 & 7)) << 3);   // kc=0
  const int sw1 = (((4 | lh) ^ (l15 & 7)) << 3);   // kc=1
  const int aoff = (((wm << 7) + l15) << 6);
  const int boff = (((wn << 5) + l15) << 6);

  f32x4 acc[8][2];
#pragma unroll
  for (int i=0;i<8;i++){
    acc[i][0] = f32x4{0.f,0.f,0.f,0.f};
    acc[i][1] = f32x4{0.f,0.f,0.f,0.f};
  }

  auto STAGE_A = [&](int tt, int s, int i){
    GLD16(gA_ + (size_t)tt*64 + (size_t)(i*8)*K, lA_ + s*16384 + i*512);
  };
  auto STAGE_B = [&](int tt, int s, int i){
    GLD16(gB_ + (size_t)tt*64 + (size_t)(i*8)*K, lB_ + s*8192 + i*512);
  };

  // prologue: stage tiles 0,1; wait tile 0 (6 of 12 outstanding = tile 1)
#pragma unroll
  for (int i=0;i<4;i++) STAGE_A(0, 0, i);
#pragma unroll
  for (int i=0;i<2;i++) STAGE_B(0, 0, i);
#pragma unroll
  for (int i=0;i<4;i++) STAGE_A(1, 1, i);
#pragma unroll
  for (int i=0;i<2;i++) STAGE_B(1, 1, i);
  asm volatile("s_waitcnt vmcnt(6)" ::: "memory");
  __builtin_amdgcn_s_barrier();

  int sl = 0, sl2 = 2;
  for (int t = 0; t < NT; ++t){
    const bool pf = (t + 2 < NT);
    const uint16_t* la = LA + sl*16384;
    const uint16_t* lb = LB + sl*8192;

    // ---- phase 0 (kc=0): 10 ds_read || 3 G-loads || 16 MFMA ----
    {
      bf16x8 af[8], bfr[2];
#pragma unroll
      for (int mi=0;mi<8;mi++) af[mi] = *(const bf16x8*)(la + aoff + mi*1024 + sw0);
#pragma unroll
      for (int ni=0;ni<2;ni++) bfr[ni] = *(const bf16x8*)(lb + boff + ni*1024 + sw0);
      if (pf){ STAGE_A(t+2, sl2, 0); STAGE_A(t+2, sl2, 1); STAGE_A(t+2, sl2, 2); }
      __builtin_amdgcn_s_barrier();
      __builtin_amdgcn_s_setprio(1);
#pragma unroll
      for (int mi=0;mi<8;mi++)
#pragma unroll
        for (int ni=0;ni<2;ni++)
          acc[mi][ni] = __builtin_amdgcn_mfma_f32_16x16x32_bf16(af[mi], bfr[ni], acc[mi][ni], 0, 0, 0);
      __builtin_amdgcn_s_setprio(0);
      __builtin_amdgcn_s_barrier();
    }
    // ---- phase 1 (kc=1): 10 ds_read || 3 G-loads || 16 MFMA ----
    {
      bf16x8 af[8], bfr[2];
#pragma unroll
      for (int mi=0;mi<8;mi++) af[mi] = *(const bf16x8*)(la + aoff + mi*1024 + sw1);
#pragma unroll
      for (int ni=0;ni<2;ni++) bfr[ni] = *(const bf16x8*)(lb + boff + ni*1024 + sw1);
      if (pf){ STAGE_A(t+2, sl2, 3); STAGE_B(t+2, sl2, 0); STAGE_B(t+2, sl2, 1); }
      __builtin_amdgcn_s_barrier();
      __builtin_amdgcn_s_setprio(1);
#pragma unroll
      for (int mi=0;mi<8;mi++)
#pragma unroll
        for (int ni=0;ni<2;ni++)
          acc[mi][ni] = __builtin_amdgcn_mfma_f32_16x16x32_bf16(af[mi], bfr[ni], acc[mi][ni], 0, 0, 0);
      __builtin_amdgcn_s_setprio(0);
    }
    // ---- boundary: counted vmcnt (tile t+1 landed; t+2 may be in flight) ----
    if (t < NT-2)       { asm volatile("s_waitcnt vmcnt(6)" ::: "memory"); }
    else if (t == NT-2) { asm volatile("s_waitcnt vmcnt(0)" ::: "memory"); }
    if (t < NT-1) __builtin_amdgcn_s_barrier();
    sl  = (sl  == 2) ? 0 : sl  + 1;
    sl2 = (sl2 == 2) ? 0 : sl2 + 1;
  }

  // ---- epilogue ----
  const int cm = (bm << 8) + (wm << 7);
  const int cn = (bn << 7) + (wn << 5);
#pragma unroll
  for (int ni=0;ni<2;ni++){
    int col = cn + ni*16 + l15;
    float bs = bias[col];
#pragma unroll
    for (int mi=0;mi<8;mi++){
#pragma unroll
      for (int r=0;r<4;r++){
        int rowg = cm + mi*16 + lh*4 + r;        // C/D: col=lane&15, row=(lane>>4)*4+r
        float v = acc[mi][ni][r] + bs;
        if (OUTB) ((uint16_t*)Cv)[(size_t)rowg * N + col] = f2bf(v);
        else      ((float*)Cv)[(size_t)rowg * N + col] = v;
      }
    }
  }
}

// ---------------- RMSNorm + RoPE in place on q,k parts of qkv ------------
__global__ __launch_bounds__(256) void rmsrope(
    uint16_t* __restrict__ qkv, const float* __restrict__ qs, const float* __restrict__ ks,
    const float* __restrict__ ct, const float* __restrict__ st)
{
  const int bx  = blockIdx.x;          // token index b*2048+t
  const int t   = bx & (L_-1);
  const int tid = threadIdx.x;
  const int h   = tid >> 4;
  const int dq  = (tid & 15) * 8;
  const int dd  = dq & 63;
  const bool hi = dq >= 64;
  const size_t base = (size_t)bx * QKVW;
  float cs[8], sn[8];
#pragma unroll
  for (int j=0;j<8;j++){ cs[j] = ct[(size_t)t*64 + dd + j]; sn[j] = st[(size_t)t*64 + dd + j]; }
#pragma unroll
  for (int qk = 0; qk < 2; qk++){
    uint16_t* p = qkv + base + qk*DM + h*HD + dq;
    ushort8 vv = *(const ushort8*)p;
    float x[8]; float ssum = 0.f;
#pragma unroll
    for (int j=0;j<8;j++){ x[j] = bf2f(vv[j]); ssum += x[j]*x[j]; }
    ssum += __shfl_xor(ssum, 1); ssum += __shfl_xor(ssum, 2);
    ssum += __shfl_xor(ssum, 4); ssum += __shfl_xor(ssum, 8);
    const float inv = rsqrtf(ssum * (1.f/128.f) + 1e-6f);
    const float* sc = qk ? ks : qs;
    float y[8];
#pragma unroll
    for (int j=0;j<8;j++) y[j] = x[j] * inv * sc[dq + j];
    float z[8];                       // partner half (d +/- 64) via lane^8
#pragma unroll
    for (int j=0;j<8;j++) z[j] = __shfl_xor(y[j], 8);
    ushort8 o;
#pragma unroll
    for (int j=0;j<8;j++){
      float r = hi ? (z[j]*sn[j] + y[j]*cs[j])
                   : (y[j]*cs[j] - z[j]*sn[j]);
      o[j] = f2bf(r);
    }
    *(ushort8*)p = o;
  }
}

// ---------------- V [b][t][h][d] -> VT [b,h][d][t] -----------------------
__global__ __launch_bounds__(256) void transpose_v(const uint16_t* __restrict__ qkv,
                                                   uint16_t* __restrict__ vt){
  __shared__ uint16_t T[64][136];
  const int tb = blockIdx.x, bh = blockIdx.y;
  const int b = bh >> 4, h = bh & 15;
  const int tid = threadIdx.x;
#pragma unroll
  for (int i=0;i<4;i++){
    int g = i*256 + tid, tt = g >> 4, c = g & 15;
    *(ushort8*)(&T[tt][c*8]) =
      *(const ushort8*)(qkv + ((size_t)b*L_ + tb*64 + tt)*QKVW + 2*DM + h*HD + c*8);
  }
  __syncthreads();
  const int d = tid >> 1, th = tid & 1;
#pragma unroll
  for (int i=0;i<4;i++){
    ushort8 o;
#pragma unroll
    for (int j=0;j<8;j++) o[j] = T[th*32 + i*8 + j][d];
    *(ushort8*)(vt + ((size_t)bh*HD + d)*L_ + tb*64 + th*32 + i*8) = o;
  }
}

// ---------------- flash attention (causal, balanced pairs) ---------------
// R4 structure (measured ~100us): grid (qp=16, bh=32); block handles q-tiles
// {qp, 31-qp}: exactly 33 K-tile iterations per block, uniform; KVBLK=64,
// 4 waves x 16 q-rows. Q in regs; K,V reg-prefetched -> padded LDS.
// Added this round: T5 setprio around MFMA clusters; T13 defer-max
// (skip m-update + rescale while per-tile max growth <= 8 in log2 domain).
__global__ __launch_bounds__(256) void flash_attn(
    const uint16_t* __restrict__ qkv, const uint16_t* __restrict__ vt,
    uint16_t* __restrict__ ao)
{
  const int qp = blockIdx.x;
  const int bh = blockIdx.y;
  const int b = bh >> 4, h = bh & 15;
  const int tid = threadIdx.x;
  const int lane = tid & 63, w = tid >> 6;
  const int l15 = lane & 15, lh = lane >> 4;

  __shared__ uint16_t Ks[64][136];
  __shared__ uint16_t Vs[128][72];
  __shared__ uint16_t Ps[4][16][72];

  const float SCL = 0.12751744f;      // (1/sqrt(128)) * log2(e)

  for (int sel = 0; sel < 2; sel++){
    const int qb = sel ? (31 - qp) : qp;

    const size_t qrow = (size_t)b * L_ + qb*64 + w*16 + l15;
    const uint16_t* qp_ = qkv + qrow * QKVW + h * HD;
    bf16x8 qf[4];
#pragma unroll
    for (int c = 0; c < 4; c++) qf[c] = *(const bf16x8*)(qp_ + c*32 + lh*8);

    float m_r[4], l_r[4];
    f32x4 oacc[8];
#pragma unroll
    for (int r = 0; r < 4; r++){ m_r[r] = -3.0e38f; l_r[r] = 0.f; }
#pragma unroll
    for (int nt = 0; nt < 8; nt++) oacc[nt] = f32x4{0.f,0.f,0.f,0.f};

    const int ntile = qb + 1;
    ushort8 rk[4], rv[4];

    // prologue: load tile 0 into regs
#pragma unroll
    for (int i = 0; i < 4; i++){
      int g = i*256 + tid, row = g >> 4, c = g & 15;
      rk[i] = *(const ushort8*)(qkv + ((size_t)b*L_ + row)*QKVW + DM + h*HD + c*8);
    }
#pragma unroll
    for (int i = 0; i < 4; i++){
      int g = i*256 + tid, d = g >> 3, c = g & 7;
      rv[i] = *(const ushort8*)(vt + ((size_t)bh*HD + d)*L_ + c*8);
    }

    for (int kt = 0; kt < ntile; kt++){
      __syncthreads();                  // prior tile's LDS reads complete
#pragma unroll
      for (int i = 0; i < 4; i++){ int g = i*256+tid; *(ushort8*)(&Ks[g>>4][(g&15)*8]) = rk[i]; }
#pragma unroll
      for (int i = 0; i < 4; i++){ int g = i*256+tid; *(ushort8*)(&Vs[g>>3][(g&7)*8]) = rv[i]; }
      __syncthreads();

      // T14: issue next tile's global loads now; latency hides under compute
      if (kt + 1 < ntile){
        const int k2 = (kt + 1) * 64;
#pragma unroll
        for (int i = 0; i < 4; i++){
          int g = i*256 + tid, row = g >> 4, c = g & 15;
          rk[i] = *(const ushort8*)(qkv + ((size_t)b*L_ + k2 + row)*QKVW + DM + h*HD + c*8);
        }
#pragma unroll
        for (int i = 0; i < 4; i++){
          int g = i*256 + tid, d = g >> 3, c = g & 7;
          rv[i] = *(const ushort8*)(vt + ((size_t)bh*HD + d)*L_ + k2 + c*8);
        }
      }

      // ---- S = Q K^T ----
      f32x4 s[4];
#pragma unroll
      for (int nt = 0; nt < 4; nt++) s[nt] = f32x4{0.f,0.f,0.f,0.f};
      __builtin_amdgcn_s_setprio(1);
#pragma unroll
      for (int c = 0; c < 4; c++){
#pragma unroll
        for (int nt = 0; nt < 4; nt++){
          bf16x8 kf = *(const bf16x8*)(&Ks[nt*16 + l15][c*32 + lh*8]);
          s[nt] = __builtin_amdgcn_mfma_f32_16x16x32_bf16(qf[c], kf, s[nt], 0, 0, 0);
        }
      }
      __builtin_amdgcn_s_setprio(0);
      // ---- scale + causal mask (log2 domain) ----
      float smv[4][4];
      const bool diag = (kt == qb);
      const int qrow_in = w*16 + lh*4;
#pragma unroll
      for (int nt = 0; nt < 4; nt++){
        int kcol = nt*16 + l15;
#pragma unroll
        for (int r = 0; r < 4; r++){
          float v = s[nt][r] * SCL;
          if (diag && (kcol > qrow_in + r)) v = -1.0e30f;
          smv[nt][r] = v;
        }
      }
      // ---- online softmax with T13 defer-max ----
      float pm[4];
#pragma unroll
      for (int r = 0; r < 4; r++){
        float v = fmaxf(fmaxf(smv[0][r], smv[1][r]), fmaxf(smv[2][r], smv[3][r]));
        v = fmaxf(v, __shfl_xor(v, 1));
        v = fmaxf(v, __shfl_xor(v, 2));
        v = fmaxf(v, __shfl_xor(v, 4));
        v = fmaxf(v, __shfl_xor(v, 8));
        pm[r] = v;
      }
      float grow = fmaxf(fmaxf(pm[0]-m_r[0], pm[1]-m_r[1]),
                         fmaxf(pm[2]-m_r[2], pm[3]-m_r[3]));
      if (!__all(grow <= 8.0f)){
        // rescale path: update m, rescale l and O
        float alpha[4];
#pragma unroll
        for (int r = 0; r < 4; r++){
          float mn = fmaxf(m_r[r], pm[r]);
          alpha[r] = exp2f(m_r[r] - mn);
          m_r[r] = mn;
          l_r[r] *= alpha[r];
        }
#pragma unroll
        for (int nt = 0; nt < 8; nt++)
#pragma unroll
          for (int r = 0; r < 4; r++) oacc[nt][r] *= alpha[r];
      }
#pragma unroll
      for (int r = 0; r < 4; r++){
        float rs = 0.f;
#pragma unroll
        for (int nt = 0; nt < 4; nt++){
          float p = exp2f(smv[nt][r] - m_r[r]);   // bounded by 2^8 when deferred
          rs += p;
          Ps[w][lh*4 + r][nt*16 + l15] = f2bf(p);
        }
        rs += __shfl_xor(rs, 1);
        rs += __shfl_xor(rs, 2);
        rs += __shfl_xor(rs, 4);
        rs += __shfl_xor(rs, 8);
        l_r[r] += rs;
      }

      asm volatile("s_waitcnt lgkmcnt(0)" ::: "memory");   // Ps writes visible (wave-private)
      // ---- O += P V ----
      __builtin_amdgcn_s_setprio(1);
#pragma unroll
      for (int kc = 0; kc < 2; kc++){
        bf16x8 pf = *(const bf16x8*)(&Ps[w][l15][kc*32 + lh*8]);
#pragma unroll
        for (int nt = 0; nt < 8; nt++){
          bf16x8 vf = *(const bf16x8*)(&Vs[nt*16 + l15][kc*32 + lh*8]);
          oacc[nt] = __builtin_amdgcn_mfma_f32_16x16x32_bf16(pf, vf, oacc[nt], 0, 0, 0);
        }
      }
      __builtin_amdgcn_s_setprio(0);
    }
    // ---- epilogue: O /= l, write [token][h*128+d] ----
    float invl[4];
#pragma unroll
    for (int r = 0; r < 4; r++) invl[r] = 1.f / l_r[r];
#pragma unroll
    for (int nt = 0; nt < 8; nt++){
#pragma unroll
      for (int r = 0; r < 4; r++){
        float v = oacc[nt][r] * invl[r];
        size_t row = (size_t)b*L_ + qb*64 + w*16 + lh*4 + r;
        ao[row * DM + h*HD + nt*16 + l15] = f2bf(v);
      }
    }
  }
}

// ---------------------------------------------------------------------------
extern "C" void kernel_launch(void* const* d_in, const int* in_sizes, int n_in,
                              void* d_out, int out_size, void* d_ws, size_t ws_size,
                              hipStream_t stream)
{
  (void)in_sizes; (void)n_in; (void)out_size; (void)ws_size;
  const float* x       = (const float*)d_in[0];
  const float* w_qkv   = (const float*)d_in[1];
  const float* b_qkv   = (const float*)d_in[2];
  const float* q_scale = (const float*)d_in[3];
  const float* k_scale = (const float*)d_in[4];
  const float* w_out   = (const float*)d_in[5];
  const float* b_out   = (const float*)d_in[6];
  float* out = (float*)d_out;

  // workspace layout (~102 MB), with lifetime-based reuse
  char* ws = (char*)d_ws;
  uint16_t* qkv   = (uint16_t*)(ws);                                   // 50,331,648 B
  uint16_t* reg1  = (uint16_t*)(ws + 50331648);                        // 16,777,216 B
  uint16_t* reg2  = (uint16_t*)(ws + 50331648 + 16777216);             // 25,165,824 B
  uint16_t* woutT = (uint16_t*)(ws + 50331648 + 16777216 + 25165824);  //  8,388,608 B
  float*    ct    = (float*)(ws + 100663296);                          //    524,288 B
  float*    st    = ct + 131072;                                       //    524,288 B

  uint16_t* xb    = reg1;   // x bf16 [4096][2048]   (dead after gemm_qkv)
  uint16_t* ao    = reg1;   // attn out bf16 [4096][2048]
  uint16_t* wqkvT = reg2;   // [6144][2048]          (dead after gemm_qkv)
  uint16_t* vt    = reg2;   // [32][128][2048]

  rope_table  <<<512, 256, 0, stream>>>(ct, st);
  cvt_f32_bf16<<<4096, 256, 0, stream>>>(x, xb, 1048576);
  transpose_w <<<dim3(32, 96), 256, 0, stream>>>(w_qkv, wqkvT, 2048, 6144);
  transpose_w <<<dim3(32, 32), 256, 0, stream>>>(w_out, woutT, 2048, 2048);
  gemm8p<1>   <<<768, 512, 0, stream>>>(xb, wqkvT, b_qkv, qkv, 4096, 6144, 2048, 48);
  rmsrope     <<<4096, 256, 0, stream>>>(qkv, q_scale, k_scale, ct, st);
  transpose_v <<<dim3(32, 32), 256, 0, stream>>>(qkv, vt);
  flash_attn  <<<dim3(16, 32), 256, 0, stream>>>(qkv, vt, ao);
  gemm8p<0>   <<<256, 512, 0, stream>>>(ao, woutT, b_out, out, 4096, 2048, 2048, 16);
}

// Round 8
// 299.500 us; speedup vs baseline: 1.5197x; 1.0488x over previous
//
#include <hip/hip_runtime.h>
#include <hip/hip_bf16.h>
#include <stdint.h>

// ---------------------------------------------------------------------------
// Fused attention block, bf16 MFMA pipeline:
//   cvt(x) / transpose(w_qkv,w_out) -> GEMM qkv (R4 gemm8p) -> rmsnorm+rope
//   -> transpose V -> flash attention (swapped QK^T lane-local softmax,
//   T5 setprio, T13 defer-max) -> GEMM out-proj (+bias, fp32)
// ---------------------------------------------------------------------------

typedef unsigned short ushort8 __attribute__((ext_vector_type(8)));
typedef short          bf16x8 __attribute__((ext_vector_type(8)));
typedef float          f32x4  __attribute__((ext_vector_type(4)));

#define B_   2
#define L_   2048
#define DM   2048
#define NH   16
#define HD   128
#define QKVW 6144   // 3*DM

__device__ __forceinline__ uint16_t f2bf(float f){
  uint32_t u = __builtin_bit_cast(uint32_t, f);
  u += 0x7FFFu + ((u >> 16) & 1u);          // RNE
  return (uint16_t)(u >> 16);
}
__device__ __forceinline__ float bf2f(uint16_t h){
  uint32_t u = ((uint32_t)h) << 16;
  return __builtin_bit_cast(float, u);
}

// async global->LDS, 16B per lane; LDS dest is wave-uniform base + lane*16
#define GLD16(gp, lp) __builtin_amdgcn_global_load_lds( \
  (const __attribute__((address_space(1))) void*)(gp),  \
  (__attribute__((address_space(3))) void*)(lp), 16, 0, 0)

// ---------------- rope cos/sin table: [2048][64] each --------------------
__global__ __launch_bounds__(256) void rope_table(float* __restrict__ ct, float* __restrict__ st){
  int i = blockIdx.x * 256 + threadIdx.x;   // 131072 threads
  int t = i >> 6, d = i & 63;
  float invf = powf(10000.f, -(float)d * (1.f/64.f));
  float s, c;
  sincosf((float)t * invf, &s, &c);
  ct[i] = c; st[i] = s;
}

// ---------------- fp32 -> bf16 convert (x) -------------------------------
__global__ __launch_bounds__(256) void cvt_f32_bf16(const float* __restrict__ x,
                                                    uint16_t* __restrict__ o, int n8){
  int i = blockIdx.x * 256 + threadIdx.x;
  if (i < n8){
    const float4* xv = (const float4*)x;
    float4 a = xv[(size_t)i*2], b = xv[(size_t)i*2+1];
    ushort8 v;
    v[0]=f2bf(a.x); v[1]=f2bf(a.y); v[2]=f2bf(a.z); v[3]=f2bf(a.w);
    v[4]=f2bf(b.x); v[5]=f2bf(b.y); v[6]=f2bf(b.z); v[7]=f2bf(b.w);
    *(ushort8*)(o + (size_t)i*8) = v;
  }
}

// ---------------- W [R][C] fp32 -> Wt [C][R] bf16 ------------------------
__global__ __launch_bounds__(256) void transpose_w(const float* __restrict__ W,
                                                   uint16_t* __restrict__ Wt, int R, int C){
  __shared__ float T[64][65];
  const int rb = blockIdx.x, cb = blockIdx.y;
  const int tid = threadIdx.x;
#pragma unroll
  for (int i=0;i<4;i++){
    int rr = i*16 + (tid >> 4);
    int cc = (tid & 15) * 4;
    float4 v = *(const float4*)(W + (size_t)(rb*64 + rr) * C + cb*64 + cc);
    T[rr][cc] = v.x; T[rr][cc+1] = v.y; T[rr][cc+2] = v.z; T[rr][cc+3] = v.w;
  }
  __syncthreads();
  const int oc = tid >> 2, rc = (tid & 3) * 16;
  ushort8 o0, o1;
#pragma unroll
  for (int j=0;j<8;j++){ o0[j] = f2bf(T[rc+j][oc]); o1[j] = f2bf(T[rc+8+j][oc]); }
  size_t ob = (size_t)(cb*64 + oc) * R + rb*64 + rc;
  *(ushort8*)(Wt + ob)     = o0;
  *(ushort8*)(Wt + ob + 8) = o1;
}

// ---------------- GEMM: C[M][N] = A[M][K] * Bt[N][K]^T + bias ------------
// R4 structure (measured ~793 TF): BM=256, BN=128, BK=64, 8 waves (2Mx4N),
// 3-slot LDS ring, prefetch distance 2, staging split 3+3 across the two
// 16-MFMA phases, counted vmcnt(6), T2 XOR-swizzle (0 conflicts), T5 setprio.
// Grids are exact multiples of 256 CUs (full rounds at 1 block/CU).
template<int OUTB>
__global__ __launch_bounds__(512, 2) void gemm8p(
    const uint16_t* __restrict__ A, const uint16_t* __restrict__ Bt,
    const float* __restrict__ bias, void* __restrict__ Cv,
    int M, int N, int K, int nbn)
{
  __shared__ uint16_t LA[3*16384];   // 3 x [256][64]
  __shared__ uint16_t LB[3*8192];    // 3 x [128][64]
  const int nwg = (M >> 8) * nbn;
  const int q8  = nwg >> 3;
  const int id  = ((int)blockIdx.x & 7) * q8 + ((int)blockIdx.x >> 3);
  const int bm = id / nbn, bn = id % nbn;
  const int tid = threadIdx.x;
  const int lane = tid & 63, w = tid >> 6;
  const int wm = w >> 2, wn = w & 3;
  const int l15 = lane & 15, lh = lane >> 4;
  const int NT = K >> 6;

  // staging: per-lane inverse-swizzled global source column
  const int qs3 = ((lane & 7) ^ ((lane >> 3) & 7)) * 8;
  const uint16_t* gA_ = A  + (size_t)((bm << 8) + (w << 5) + (lane >> 3)) * K + qs3;
  const uint16_t* gB_ = Bt + (size_t)((bn << 7) + (w << 4) + (lane >> 3)) * K + qs3;
  uint16_t* lA_ = LA + (w << 11);    // wave-uniform LDS bases
  uint16_t* lB_ = LB + (w << 10);

  // fragment-read swizzled offsets (elements)
  const int sw0 = ((lh       ^ (l15 & 7)) << 3);   // kc=0
  const int sw1 = (((4 | lh) ^ (l15 & 7)) << 3);   // kc=1
  const int aoff = (((wm << 7) + l15) << 6);
  const int boff = (((wn << 5) + l15) << 6);

  f32x4 acc[8][2];
#pragma unroll
  for (int i=0;i<8;i++){
    acc[i][0] = f32x4{0.f,0.f,0.f,0.f};
    acc[i][1] = f32x4{0.f,0.f,0.f,0.f};
  }

  auto STAGE_A = [&](int tt, int s, int i){
    GLD16(gA_ + (size_t)tt*64 + (size_t)(i*8)*K, lA_ + s*16384 + i*512);
  };
  auto STAGE_B = [&](int tt, int s, int i){
    GLD16(gB_ + (size_t)tt*64 + (size_t)(i*8)*K, lB_ + s*8192 + i*512);
  };

  // prologue: stage tiles 0,1; wait tile 0 (6 of 12 outstanding = tile 1)
#pragma unroll
  for (int i=0;i<4;i++) STAGE_A(0, 0, i);
#pragma unroll
  for (int i=0;i<2;i++) STAGE_B(0, 0, i);
#pragma unroll
  for (int i=0;i<4;i++) STAGE_A(1, 1, i);
#pragma unroll
  for (int i=0;i<2;i++) STAGE_B(1, 1, i);
  asm volatile("s_waitcnt vmcnt(6)" ::: "memory");
  __builtin_amdgcn_s_barrier();

  int sl = 0, sl2 = 2;
  for (int t = 0; t < NT; ++t){
    const bool pf = (t + 2 < NT);
    const uint16_t* la = LA + sl*16384;
    const uint16_t* lb = LB + sl*8192;

    // ---- phase 0 (kc=0): 10 ds_read || 3 G-loads || 16 MFMA ----
    {
      bf16x8 af[8], bfr[2];
#pragma unroll
      for (int mi=0;mi<8;mi++) af[mi] = *(const bf16x8*)(la + aoff + mi*1024 + sw0);
#pragma unroll
      for (int ni=0;ni<2;ni++) bfr[ni] = *(const bf16x8*)(lb + boff + ni*1024 + sw0);
      if (pf){ STAGE_A(t+2, sl2, 0); STAGE_A(t+2, sl2, 1); STAGE_A(t+2, sl2, 2); }
      __builtin_amdgcn_s_barrier();
      __builtin_amdgcn_s_setprio(1);
#pragma unroll
      for (int mi=0;mi<8;mi++)
#pragma unroll
        for (int ni=0;ni<2;ni++)
          acc[mi][ni] = __builtin_amdgcn_mfma_f32_16x16x32_bf16(af[mi], bfr[ni], acc[mi][ni], 0, 0, 0);
      __builtin_amdgcn_s_setprio(0);
      __builtin_amdgcn_s_barrier();
    }
    // ---- phase 1 (kc=1): 10 ds_read || 3 G-loads || 16 MFMA ----
    {
      bf16x8 af[8], bfr[2];
#pragma unroll
      for (int mi=0;mi<8;mi++) af[mi] = *(const bf16x8*)(la + aoff + mi*1024 + sw1);
#pragma unroll
      for (int ni=0;ni<2;ni++) bfr[ni] = *(const bf16x8*)(lb + boff + ni*1024 + sw1);
      if (pf){ STAGE_A(t+2, sl2, 3); STAGE_B(t+2, sl2, 0); STAGE_B(t+2, sl2, 1); }
      __builtin_amdgcn_s_barrier();
      __builtin_amdgcn_s_setprio(1);
#pragma unroll
      for (int mi=0;mi<8;mi++)
#pragma unroll
        for (int ni=0;ni<2;ni++)
          acc[mi][ni] = __builtin_amdgcn_mfma_f32_16x16x32_bf16(af[mi], bfr[ni], acc[mi][ni], 0, 0, 0);
      __builtin_amdgcn_s_setprio(0);
    }
    // ---- boundary: counted vmcnt (tile t+1 landed; t+2 may be in flight) ----
    if (t < NT-2)       { asm volatile("s_waitcnt vmcnt(6)" ::: "memory"); }
    else if (t == NT-2) { asm volatile("s_waitcnt vmcnt(0)" ::: "memory"); }
    if (t < NT-1) __builtin_amdgcn_s_barrier();
    sl  = (sl  == 2) ? 0 : sl  + 1;
    sl2 = (sl2 == 2) ? 0 : sl2 + 1;
  }

  // ---- epilogue ----
  const int cm = (bm << 8) + (wm << 7);
  const int cn = (bn << 7) + (wn << 5);
#pragma unroll
  for (int ni=0;ni<2;ni++){
    int col = cn + ni*16 + l15;
    float bs = bias[col];
#pragma unroll
    for (int mi=0;mi<8;mi++){
#pragma unroll
      for (int r=0;r<4;r++){
        int rowg = cm + mi*16 + lh*4 + r;        // C/D: col=lane&15, row=(lane>>4)*4+r
        float v = acc[mi][ni][r] + bs;
        if (OUTB) ((uint16_t*)Cv)[(size_t)rowg * N + col] = f2bf(v);
        else      ((float*)Cv)[(size_t)rowg * N + col] = v;
      }
    }
  }
}

// ---------------- RMSNorm + RoPE in place on q,k parts of qkv ------------
__global__ __launch_bounds__(256) void rmsrope(
    uint16_t* __restrict__ qkv, const float* __restrict__ qs, const float* __restrict__ ks,
    const float* __restrict__ ct, const float* __restrict__ st)
{
  const int bx  = blockIdx.x;          // token index b*2048+t
  const int t   = bx & (L_-1);
  const int tid = threadIdx.x;
  const int h   = tid >> 4;
  const int dq  = (tid & 15) * 8;
  const int dd  = dq & 63;
  const bool hi = dq >= 64;
  const size_t base = (size_t)bx * QKVW;
  float cs[8], sn[8];
#pragma unroll
  for (int j=0;j<8;j++){ cs[j] = ct[(size_t)t*64 + dd + j]; sn[j] = st[(size_t)t*64 + dd + j]; }
#pragma unroll
  for (int qk = 0; qk < 2; qk++){
    uint16_t* p = qkv + base + qk*DM + h*HD + dq;
    ushort8 vv = *(const ushort8*)p;
    float x[8]; float ssum = 0.f;
#pragma unroll
    for (int j=0;j<8;j++){ x[j] = bf2f(vv[j]); ssum += x[j]*x[j]; }
    ssum += __shfl_xor(ssum, 1); ssum += __shfl_xor(ssum, 2);
    ssum += __shfl_xor(ssum, 4); ssum += __shfl_xor(ssum, 8);
    const float inv = rsqrtf(ssum * (1.f/128.f) + 1e-6f);
    const float* sc = qk ? ks : qs;
    float y[8];
#pragma unroll
    for (int j=0;j<8;j++) y[j] = x[j] * inv * sc[dq + j];
    float z[8];                       // partner half (d +/- 64) via lane^8
#pragma unroll
    for (int j=0;j<8;j++) z[j] = __shfl_xor(y[j], 8);
    ushort8 o;
#pragma unroll
    for (int j=0;j<8;j++){
      float r = hi ? (z[j]*sn[j] + y[j]*cs[j])
                   : (y[j]*cs[j] - z[j]*sn[j]);
      o[j] = f2bf(r);
    }
    *(ushort8*)p = o;
  }
}

// ---------------- V [b][t][h][d] -> VT [b,h][d][t] -----------------------
__global__ __launch_bounds__(256) void transpose_v(const uint16_t* __restrict__ qkv,
                                                   uint16_t* __restrict__ vt){
  __shared__ uint16_t T[64][136];
  const int tb = blockIdx.x, bh = blockIdx.y;
  const int b = bh >> 4, h = bh & 15;
  const int tid = threadIdx.x;
#pragma unroll
  for (int i=0;i<4;i++){
    int g = i*256 + tid, tt = g >> 4, c = g & 15;
    *(ushort8*)(&T[tt][c*8]) =
      *(const ushort8*)(qkv + ((size_t)b*L_ + tb*64 + tt)*QKVW + 2*DM + h*HD + c*8);
  }
  __syncthreads();
  const int d = tid >> 1, th = tid & 1;
#pragma unroll
  for (int i=0;i<4;i++){
    ushort8 o;
#pragma unroll
    for (int j=0;j<8;j++) o[j] = T[th*32 + i*8 + j][d];
    *(ushort8*)(vt + ((size_t)bh*HD + d)*L_ + tb*64 + th*32 + i*8) = o;
  }
}

// ---------------- flash attention (causal, balanced pairs) ---------------
// grid (qp=16, bh=32); block handles q-tiles {qp, 31-qp}: 33 K-tile iters,
// uniform. KVBLK=64, 4 waves x 16 q-rows. Q in regs; K,V reg-prefetched LDS.
// SWAPPED QK^T (mfma(K,Q)): S layout [k][q] -> lane holds 16 k-vals for ONE
// q (=lane&15): softmax reduce = in-lane chain + 2 shuffles (xor16/32);
// P stores as 4x ds_write_b64. alpha/l redistributed to oacc rows (q=lh*4+r)
// via 4 __shfl on the (T13-rare) rescale path / epilogue only.
__global__ __launch_bounds__(256) void flash_attn(
    const uint16_t* __restrict__ qkv, const uint16_t* __restrict__ vt,
    uint16_t* __restrict__ ao)
{
  const int qp = blockIdx.x;
  const int bh = blockIdx.y;
  const int b = bh >> 4, h = bh & 15;
  const int tid = threadIdx.x;
  const int lane = tid & 63, w = tid >> 6;
  const int l15 = lane & 15, lh = lane >> 4;

  __shared__ uint16_t Ks[64][136];
  __shared__ uint16_t Vs[128][72];
  __shared__ uint16_t Ps[4][16][72];

  const float SCL = 0.12751744f;      // (1/sqrt(128)) * log2(e)

  for (int sel = 0; sel < 2; sel++){
    const int qb = sel ? (31 - qp) : qp;

    // Q fragments: wave w owns q rows qb*64 + w*16 + (0..15); lane's q = l15
    const size_t qrow = (size_t)b * L_ + qb*64 + w*16 + l15;
    const uint16_t* qp_ = qkv + qrow * QKVW + h * HD;
    bf16x8 qf[4];
#pragma unroll
    for (int c = 0; c < 4; c++) qf[c] = *(const bf16x8*)(qp_ + c*32 + lh*8);

    float m_s = -3.0e38f, l_s = 0.f;   // per-lane scalars for q = l15
    f32x4 oacc[8];
#pragma unroll
    for (int nt = 0; nt < 8; nt++) oacc[nt] = f32x4{0.f,0.f,0.f,0.f};

    const int ntile = qb + 1;
    ushort8 rk[4], rv[4];

    // prologue: load tile 0 into regs
#pragma unroll
    for (int i = 0; i < 4; i++){
      int g = i*256 + tid, row = g >> 4, c = g & 15;
      rk[i] = *(const ushort8*)(qkv + ((size_t)b*L_ + row)*QKVW + DM + h*HD + c*8);
    }
#pragma unroll
    for (int i = 0; i < 4; i++){
      int g = i*256 + tid, d = g >> 3, c = g & 7;
      rv[i] = *(const ushort8*)(vt + ((size_t)bh*HD + d)*L_ + c*8);
    }

    for (int kt = 0; kt < ntile; kt++){
      __syncthreads();                  // prior tile's LDS reads complete
#pragma unroll
      for (int i = 0; i < 4; i++){ int g = i*256+tid; *(ushort8*)(&Ks[g>>4][(g&15)*8]) = rk[i]; }
#pragma unroll
      for (int i = 0; i < 4; i++){ int g = i*256+tid; *(ushort8*)(&Vs[g>>3][(g&7)*8]) = rv[i]; }
      __syncthreads();

      // T14: issue next tile's global loads now; latency hides under compute
      if (kt + 1 < ntile){
        const int k2 = (kt + 1) * 64;
#pragma unroll
        for (int i = 0; i < 4; i++){
          int g = i*256 + tid, row = g >> 4, c = g & 15;
          rk[i] = *(const ushort8*)(qkv + ((size_t)b*L_ + k2 + row)*QKVW + DM + h*HD + c*8);
        }
#pragma unroll
        for (int i = 0; i < 4; i++){
          int g = i*256 + tid, d = g >> 3, c = g & 7;
          rv[i] = *(const ushort8*)(vt + ((size_t)bh*HD + d)*L_ + k2 + c*8);
        }
      }

      // ---- S^T = K Q^T : s[nt][r] = S[k = nt*16+lh*4+r][q = l15] ----
      f32x4 s[4];
#pragma unroll
      for (int nt = 0; nt < 4; nt++) s[nt] = f32x4{0.f,0.f,0.f,0.f};
      __builtin_amdgcn_s_setprio(1);
#pragma unroll
      for (int c = 0; c < 4; c++){
#pragma unroll
        for (int nt = 0; nt < 4; nt++){
          bf16x8 kf = *(const bf16x8*)(&Ks[nt*16 + l15][c*32 + lh*8]);
          s[nt] = __builtin_amdgcn_mfma_f32_16x16x32_bf16(kf, qf[c], s[nt], 0, 0, 0);
        }
      }
      __builtin_amdgcn_s_setprio(0);

      // ---- scale + causal mask (log2 domain) ----
      const bool diag = (kt == qb);
      const int qg = w*16 + l15;            // q within block
      const int kb = lh*4;                  // k base within each 16-k tile
#pragma unroll
      for (int nt = 0; nt < 4; nt++){
#pragma unroll
        for (int r = 0; r < 4; r++){
          float v = s[nt][r] * SCL;
          if (diag && (nt*16 + kb + r > qg)) v = -1.0e30f;
          s[nt][r] = v;
        }
      }
      // ---- lane-local max over 16 k + 2 cross-lh shuffles ----
      float pm = s[0][0];
#pragma unroll
      for (int nt = 0; nt < 4; nt++)
#pragma unroll
        for (int r = 0; r < 4; r++) pm = fmaxf(pm, s[nt][r]);
      pm = fmaxf(pm, __shfl_xor(pm, 16));
      pm = fmaxf(pm, __shfl_xor(pm, 32));
      // ---- T13 defer-max ----
      if (!__all(pm - m_s <= 8.0f)){
        float mn = fmaxf(m_s, pm);
        float alpha = exp2f(m_s - mn);
        m_s = mn; l_s *= alpha;
        float ar[4];
#pragma unroll
        for (int r = 0; r < 4; r++) ar[r] = __shfl(alpha, lh*4 + r);
#pragma unroll
        for (int nt = 0; nt < 8; nt++)
#pragma unroll
          for (int r = 0; r < 4; r++) oacc[nt][r] *= ar[r];
      }
      // ---- P = exp2(S - m), pack 4 consecutive k, store b64; sum ----
      float rs = 0.f;
#pragma unroll
      for (int nt = 0; nt < 4; nt++){
        float p0 = exp2f(s[nt][0] - m_s);
        float p1 = exp2f(s[nt][1] - m_s);
        float p2 = exp2f(s[nt][2] - m_s);
        float p3 = exp2f(s[nt][3] - m_s);
        rs += (p0 + p1) + (p2 + p3);
        uint2 pk;
        pk.x = (uint32_t)f2bf(p0) | ((uint32_t)f2bf(p1) << 16);
        pk.y = (uint32_t)f2bf(p2) | ((uint32_t)f2bf(p3) << 16);
        *(uint2*)(&Ps[w][l15][nt*16 + kb]) = pk;
      }
      rs += __shfl_xor(rs, 16);
      rs += __shfl_xor(rs, 32);
      l_s += rs;

      asm volatile("s_waitcnt lgkmcnt(0)" ::: "memory");   // Ps writes visible (wave-private)
      // ---- O += P V : A=P[16q][64k] (LDS), B=V[64k][128d] (LDS) ----
      __builtin_amdgcn_s_setprio(1);
#pragma unroll
      for (int kc = 0; kc < 2; kc++){
        bf16x8 pf = *(const bf16x8*)(&Ps[w][l15][kc*32 + lh*8]);
#pragma unroll
        for (int nt = 0; nt < 8; nt++){
          bf16x8 vf = *(const bf16x8*)(&Vs[nt*16 + l15][kc*32 + lh*8]);
          oacc[nt] = __builtin_amdgcn_mfma_f32_16x16x32_bf16(pf, vf, oacc[nt], 0, 0, 0);
        }
      }
      __builtin_amdgcn_s_setprio(0);
    }
    // ---- epilogue: redistribute l to oacc rows, O /= l, write ----
    float invl[4];
#pragma unroll
    for (int r = 0; r < 4; r++) invl[r] = 1.f / __shfl(l_s, lh*4 + r);
#pragma unroll
    for (int nt = 0; nt < 8; nt++){
#pragma unroll
      for (int r = 0; r < 4; r++){
        float v = oacc[nt][r] * invl[r];
        size_t row = (size_t)b*L_ + qb*64 + w*16 + lh*4 + r;
        ao[row * DM + h*HD + nt*16 + l15] = f2bf(v);
      }
    }
  }
}

// ---------------------------------------------------------------------------
extern "C" void kernel_launch(void* const* d_in, const int* in_sizes, int n_in,
                              void* d_out, int out_size, void* d_ws, size_t ws_size,
                              hipStream_t stream)
{
  (void)in_sizes; (void)n_in; (void)out_size; (void)ws_size;
  const float* x       = (const float*)d_in[0];
  const float* w_qkv   = (const float*)d_in[1];
  const float* b_qkv   = (const float*)d_in[2];
  const float* q_scale = (const float*)d_in[3];
  const float* k_scale = (const float*)d_in[4];
  const float* w_out   = (const float*)d_in[5];
  const float* b_out   = (const float*)d_in[6];
  float* out = (float*)d_out;

  // workspace layout (~102 MB), with lifetime-based reuse
  char* ws = (char*)d_ws;
  uint16_t* qkv   = (uint16_t*)(ws);                                   // 50,331,648 B
  uint16_t* reg1  = (uint16_t*)(ws + 50331648);                        // 16,777,216 B
  uint16_t* reg2  = (uint16_t*)(ws + 50331648 + 16777216);             // 25,165,824 B
  uint16_t* woutT = (uint16_t*)(ws + 50331648 + 16777216 + 25165824);  //  8,388,608 B
  float*    ct    = (float*)(ws + 100663296);                          //    524,288 B
  float*    st    = ct + 131072;                                       //    524,288 B

  uint16_t* xb    = reg1;   // x bf16 [4096][2048]   (dead after gemm_qkv)
  uint16_t* ao    = reg1;   // attn out bf16 [4096][2048]
  uint16_t* wqkvT = reg2;   // [6144][2048]          (dead after gemm_qkv)
  uint16_t* vt    = reg2;   // [32][128][2048]

  rope_table  <<<512, 256, 0, stream>>>(ct, st);
  cvt_f32_bf16<<<4096, 256, 0, stream>>>(x, xb, 1048576);
  transpose_w <<<dim3(32, 96), 256, 0, stream>>>(w_qkv, wqkvT, 2048, 6144);
  transpose_w <<<dim3(32, 32), 256, 0, stream>>>(w_out, woutT, 2048, 2048);
  gemm8p<1>   <<<768, 512, 0, stream>>>(xb, wqkvT, b_qkv, qkv, 4096, 6144, 2048, 48);
  rmsrope     <<<4096, 256, 0, stream>>>(qkv, q_scale, k_scale, ct, st);
  transpose_v <<<dim3(32, 32), 256, 0, stream>>>(qkv, vt);
  flash_attn  <<<dim3(16, 32), 256, 0, stream>>>(qkv, vt, ao);
  gemm8p<0>   <<<256, 512, 0, stream>>>(ao, woutT, b_out, out, 4096, 2048, 2048, 16);
}

// Round 9
// 295.123 us; speedup vs baseline: 1.5423x; 1.0148x over previous
//
#include <hip/hip_runtime.h>
#include <hip/hip_bf16.h>
#include <stdint.h>

// ---------------------------------------------------------------------------
// Fused attention block, bf16 MFMA pipeline:
//   cvt(x) / transpose(w_qkv,w_out) -> GEMM qkv (gemm8p, 64x64/wave) ->
//   rmsnorm+rope -> transpose V -> flash attention (swapped QK^T lane-local
//   softmax, T5, T13) -> GEMM out-proj (+bias, fp32)
// ---------------------------------------------------------------------------

typedef unsigned short ushort8 __attribute__((ext_vector_type(8)));
typedef short          bf16x8 __attribute__((ext_vector_type(8)));
typedef float          f32x4  __attribute__((ext_vector_type(4)));

#define B_   2
#define L_   2048
#define DM   2048
#define NH   16
#define HD   128
#define QKVW 6144   // 3*DM

__device__ __forceinline__ uint16_t f2bf(float f){
  uint32_t u = __builtin_bit_cast(uint32_t, f);
  u += 0x7FFFu + ((u >> 16) & 1u);          // RNE
  return (uint16_t)(u >> 16);
}
__device__ __forceinline__ float bf2f(uint16_t h){
  uint32_t u = ((uint32_t)h) << 16;
  return __builtin_bit_cast(float, u);
}

// async global->LDS, 16B per lane; LDS dest is wave-uniform base + lane*16
#define GLD16(gp, lp) __builtin_amdgcn_global_load_lds( \
  (const __attribute__((address_space(1))) void*)(gp),  \
  (__attribute__((address_space(3))) void*)(lp), 16, 0, 0)

// ---------------- rope cos/sin table: [2048][64] each --------------------
__global__ __launch_bounds__(256) void rope_table(float* __restrict__ ct, float* __restrict__ st){
  int i = blockIdx.x * 256 + threadIdx.x;   // 131072 threads
  int t = i >> 6, d = i & 63;
  float invf = powf(10000.f, -(float)d * (1.f/64.f));
  float s, c;
  sincosf((float)t * invf, &s, &c);
  ct[i] = c; st[i] = s;
}

// ---------------- fp32 -> bf16 convert (x) -------------------------------
__global__ __launch_bounds__(256) void cvt_f32_bf16(const float* __restrict__ x,
                                                    uint16_t* __restrict__ o, int n8){
  int i = blockIdx.x * 256 + threadIdx.x;
  if (i < n8){
    const float4* xv = (const float4*)x;
    float4 a = xv[(size_t)i*2], b = xv[(size_t)i*2+1];
    ushort8 v;
    v[0]=f2bf(a.x); v[1]=f2bf(a.y); v[2]=f2bf(a.z); v[3]=f2bf(a.w);
    v[4]=f2bf(b.x); v[5]=f2bf(b.y); v[6]=f2bf(b.z); v[7]=f2bf(b.w);
    *(ushort8*)(o + (size_t)i*8) = v;
  }
}

// ---------------- W [R][C] fp32 -> Wt [C][R] bf16 ------------------------
__global__ __launch_bounds__(256) void transpose_w(const float* __restrict__ W,
                                                   uint16_t* __restrict__ Wt, int R, int C){
  __shared__ float T[64][65];
  const int rb = blockIdx.x, cb = blockIdx.y;
  const int tid = threadIdx.x;
#pragma unroll
  for (int i=0;i<4;i++){
    int rr = i*16 + (tid >> 4);
    int cc = (tid & 15) * 4;
    float4 v = *(const float4*)(W + (size_t)(rb*64 + rr) * C + cb*64 + cc);
    T[rr][cc] = v.x; T[rr][cc+1] = v.y; T[rr][cc+2] = v.z; T[rr][cc+3] = v.w;
  }
  __syncthreads();
  const int oc = tid >> 2, rc = (tid & 3) * 16;
  ushort8 o0, o1;
#pragma unroll
  for (int j=0;j<8;j++){ o0[j] = f2bf(T[rc+j][oc]); o1[j] = f2bf(T[rc+8+j][oc]); }
  size_t ob = (size_t)(cb*64 + oc) * R + rb*64 + rc;
  *(ushort8*)(Wt + ob)     = o0;
  *(ushort8*)(Wt + ob + 8) = o1;
}

// ---------------- GEMM: C[M][N] = A[M][K] * Bt[N][K]^T + bias ------------
// R4 schedule (3-slot ring, prefetch-2, staging split 3+3 across two 16-MFMA
// phases, counted vmcnt(6), T2 XOR-swizzle, T5 setprio) with SQUARE per-wave
// output: 8 waves as 4M x 2N, per-wave 64x64, acc[4][4].
// LDS-pipe read pressure drops from 10 to 8 ds_read_b128 per phase per wave
// ((M_rep+N_rep) minimized at fixed M_rep*N_rep) - the measured limiter.
template<int OUTB>
__global__ __launch_bounds__(512, 2) void gemm8p(
    const uint16_t* __restrict__ A, const uint16_t* __restrict__ Bt,
    const float* __restrict__ bias, void* __restrict__ Cv,
    int M, int N, int K, int nbn)
{
  __shared__ uint16_t LA[3*16384];   // 3 x [256][64]
  __shared__ uint16_t LB[3*8192];    // 3 x [128][64]
  const int nwg = (M >> 8) * nbn;
  const int q8  = nwg >> 3;
  const int id  = ((int)blockIdx.x & 7) * q8 + ((int)blockIdx.x >> 3);
  const int bm = id / nbn, bn = id % nbn;
  const int tid = threadIdx.x;
  const int lane = tid & 63, w = tid >> 6;
  const int wm = w & 3, wn = w >> 2;          // 4M x 2N, 64x64 per wave
  const int l15 = lane & 15, lh = lane >> 4;
  const int NT = K >> 6;

  // staging: per-lane inverse-swizzled global source column
  const int qs3 = ((lane & 7) ^ ((lane >> 3) & 7)) * 8;
  const uint16_t* gA_ = A  + (size_t)((bm << 8) + (w << 5) + (lane >> 3)) * K + qs3;
  const uint16_t* gB_ = Bt + (size_t)((bn << 7) + (w << 4) + (lane >> 3)) * K + qs3;
  uint16_t* lA_ = LA + (w << 11);    // wave-uniform LDS bases
  uint16_t* lB_ = LB + (w << 10);

  // fragment-read swizzled offsets (elements)
  const int sw0 = ((lh       ^ (l15 & 7)) << 3);   // kc=0
  const int sw1 = (((4 | lh) ^ (l15 & 7)) << 3);   // kc=1
  const int aoff = (((wm << 6) + l15) << 6);       // rows wm*64 + mi*16 + l15
  const int boff = (((wn << 6) + l15) << 6);       // rows wn*64 + ni*16 + l15

  f32x4 acc[4][4];
#pragma unroll
  for (int i=0;i<4;i++)
#pragma unroll
    for (int j=0;j<4;j++) acc[i][j] = f32x4{0.f,0.f,0.f,0.f};

  auto STAGE_A = [&](int tt, int s, int i){
    GLD16(gA_ + (size_t)tt*64 + (size_t)(i*8)*K, lA_ + s*16384 + i*512);
  };
  auto STAGE_B = [&](int tt, int s, int i){
    GLD16(gB_ + (size_t)tt*64 + (size_t)(i*8)*K, lB_ + s*8192 + i*512);
  };

  // prologue: stage tiles 0,1; wait tile 0 (6 of 12 outstanding = tile 1)
#pragma unroll
  for (int i=0;i<4;i++) STAGE_A(0, 0, i);
#pragma unroll
  for (int i=0;i<2;i++) STAGE_B(0, 0, i);
#pragma unroll
  for (int i=0;i<4;i++) STAGE_A(1, 1, i);
#pragma unroll
  for (int i=0;i<2;i++) STAGE_B(1, 1, i);
  asm volatile("s_waitcnt vmcnt(6)" ::: "memory");
  __builtin_amdgcn_s_barrier();

  int sl = 0, sl2 = 2;
  for (int t = 0; t < NT; ++t){
    const bool pf = (t + 2 < NT);
    const uint16_t* la = LA + sl*16384;
    const uint16_t* lb = LB + sl*8192;

    // ---- phase 0 (kc=0): 8 ds_read || 3 G-loads || 16 MFMA ----
    {
      bf16x8 af[4], bfr[4];
#pragma unroll
      for (int mi=0;mi<4;mi++) af[mi] = *(const bf16x8*)(la + aoff + mi*1024 + sw0);
#pragma unroll
      for (int ni=0;ni<4;ni++) bfr[ni] = *(const bf16x8*)(lb + boff + ni*1024 + sw0);
      if (pf){ STAGE_A(t+2, sl2, 0); STAGE_A(t+2, sl2, 1); STAGE_A(t+2, sl2, 2); }
      __builtin_amdgcn_s_barrier();
      __builtin_amdgcn_s_setprio(1);
#pragma unroll
      for (int mi=0;mi<4;mi++)
#pragma unroll
        for (int ni=0;ni<4;ni++)
          acc[mi][ni] = __builtin_amdgcn_mfma_f32_16x16x32_bf16(af[mi], bfr[ni], acc[mi][ni], 0, 0, 0);
      __builtin_amdgcn_s_setprio(0);
      __builtin_amdgcn_s_barrier();
    }
    // ---- phase 1 (kc=1): 8 ds_read || 3 G-loads || 16 MFMA ----
    {
      bf16x8 af[4], bfr[4];
#pragma unroll
      for (int mi=0;mi<4;mi++) af[mi] = *(const bf16x8*)(la + aoff + mi*1024 + sw1);
#pragma unroll
      for (int ni=0;ni<4;ni++) bfr[ni] = *(const bf16x8*)(lb + boff + ni*1024 + sw1);
      if (pf){ STAGE_A(t+2, sl2, 3); STAGE_B(t+2, sl2, 0); STAGE_B(t+2, sl2, 1); }
      __builtin_amdgcn_s_barrier();
      __builtin_amdgcn_s_setprio(1);
#pragma unroll
      for (int mi=0;mi<4;mi++)
#pragma unroll
        for (int ni=0;ni<4;ni++)
          acc[mi][ni] = __builtin_amdgcn_mfma_f32_16x16x32_bf16(af[mi], bfr[ni], acc[mi][ni], 0, 0, 0);
      __builtin_amdgcn_s_setprio(0);
    }
    // ---- boundary: counted vmcnt (tile t+1 landed; t+2 may be in flight) ----
    if (t < NT-2)       { asm volatile("s_waitcnt vmcnt(6)" ::: "memory"); }
    else if (t == NT-2) { asm volatile("s_waitcnt vmcnt(0)" ::: "memory"); }
    if (t < NT-1) __builtin_amdgcn_s_barrier();
    sl  = (sl  == 2) ? 0 : sl  + 1;
    sl2 = (sl2 == 2) ? 0 : sl2 + 1;
  }

  // ---- epilogue ----
  const int cm = (bm << 8) + (wm << 6);
  const int cn = (bn << 7) + (wn << 6);
#pragma unroll
  for (int ni=0;ni<4;ni++){
    int col = cn + ni*16 + l15;
    float bs = bias[col];
#pragma unroll
    for (int mi=0;mi<4;mi++){
#pragma unroll
      for (int r=0;r<4;r++){
        int rowg = cm + mi*16 + lh*4 + r;        // C/D: col=lane&15, row=(lane>>4)*4+r
        float v = acc[mi][ni][r] + bs;
        if (OUTB) ((uint16_t*)Cv)[(size_t)rowg * N + col] = f2bf(v);
        else      ((float*)Cv)[(size_t)rowg * N + col] = v;
      }
    }
  }
}

// ---------------- RMSNorm + RoPE in place on q,k parts of qkv ------------
__global__ __launch_bounds__(256) void rmsrope(
    uint16_t* __restrict__ qkv, const float* __restrict__ qs, const float* __restrict__ ks,
    const float* __restrict__ ct, const float* __restrict__ st)
{
  const int bx  = blockIdx.x;          // token index b*2048+t
  const int t   = bx & (L_-1);
  const int tid = threadIdx.x;
  const int h   = tid >> 4;
  const int dq  = (tid & 15) * 8;
  const int dd  = dq & 63;
  const bool hi = dq >= 64;
  const size_t base = (size_t)bx * QKVW;
  float cs[8], sn[8];
#pragma unroll
  for (int j=0;j<8;j++){ cs[j] = ct[(size_t)t*64 + dd + j]; sn[j] = st[(size_t)t*64 + dd + j]; }
#pragma unroll
  for (int qk = 0; qk < 2; qk++){
    uint16_t* p = qkv + base + qk*DM + h*HD + dq;
    ushort8 vv = *(const ushort8*)p;
    float x[8]; float ssum = 0.f;
#pragma unroll
    for (int j=0;j<8;j++){ x[j] = bf2f(vv[j]); ssum += x[j]*x[j]; }
    ssum += __shfl_xor(ssum, 1); ssum += __shfl_xor(ssum, 2);
    ssum += __shfl_xor(ssum, 4); ssum += __shfl_xor(ssum, 8);
    const float inv = rsqrtf(ssum * (1.f/128.f) + 1e-6f);
    const float* sc = qk ? ks : qs;
    float y[8];
#pragma unroll
    for (int j=0;j<8;j++) y[j] = x[j] * inv * sc[dq + j];
    float z[8];                       // partner half (d +/- 64) via lane^8
#pragma unroll
    for (int j=0;j<8;j++) z[j] = __shfl_xor(y[j], 8);
    ushort8 o;
#pragma unroll
    for (int j=0;j<8;j++){
      float r = hi ? (z[j]*sn[j] + y[j]*cs[j])
                   : (y[j]*cs[j] - z[j]*sn[j]);
      o[j] = f2bf(r);
    }
    *(ushort8*)p = o;
  }
}

// ---------------- V [b][t][h][d] -> VT [b,h][d][t] -----------------------
__global__ __launch_bounds__(256) void transpose_v(const uint16_t* __restrict__ qkv,
                                                   uint16_t* __restrict__ vt){
  __shared__ uint16_t T[64][136];
  const int tb = blockIdx.x, bh = blockIdx.y;
  const int b = bh >> 4, h = bh & 15;
  const int tid = threadIdx.x;
#pragma unroll
  for (int i=0;i<4;i++){
    int g = i*256 + tid, tt = g >> 4, c = g & 15;
    *(ushort8*)(&T[tt][c*8]) =
      *(const ushort8*)(qkv + ((size_t)b*L_ + tb*64 + tt)*QKVW + 2*DM + h*HD + c*8);
  }
  __syncthreads();
  const int d = tid >> 1, th = tid & 1;
#pragma unroll
  for (int i=0;i<4;i++){
    ushort8 o;
#pragma unroll
    for (int j=0;j<8;j++) o[j] = T[th*32 + i*8 + j][d];
    *(ushort8*)(vt + ((size_t)bh*HD + d)*L_ + tb*64 + th*32 + i*8) = o;
  }
}

// ---------------- flash attention (causal, balanced pairs) ---------------
// grid (qp=16, bh=32); block handles q-tiles {qp, 31-qp}: 33 K-tile iters,
// uniform. KVBLK=64, 4 waves x 16 q-rows. Q in regs; K,V reg-prefetched LDS.
// SWAPPED QK^T (mfma(K,Q)): S layout [k][q] -> lane holds 16 k-vals for ONE
// q (=lane&15): softmax reduce = in-lane chain + 2 shuffles (xor16/32);
// P stores as 4x ds_write_b64. alpha/l redistributed to oacc rows (q=lh*4+r)
// via 4 __shfl on the (T13-rare) rescale path / epilogue only.
__global__ __launch_bounds__(256) void flash_attn(
    const uint16_t* __restrict__ qkv, const uint16_t* __restrict__ vt,
    uint16_t* __restrict__ ao)
{
  const int qp = blockIdx.x;
  const int bh = blockIdx.y;
  const int b = bh >> 4, h = bh & 15;
  const int tid = threadIdx.x;
  const int lane = tid & 63, w = tid >> 6;
  const int l15 = lane & 15, lh = lane >> 4;

  __shared__ uint16_t Ks[64][136];
  __shared__ uint16_t Vs[128][72];
  __shared__ uint16_t Ps[4][16][72];

  const float SCL = 0.12751744f;      // (1/sqrt(128)) * log2(e)

  for (int sel = 0; sel < 2; sel++){
    const int qb = sel ? (31 - qp) : qp;

    // Q fragments: wave w owns q rows qb*64 + w*16 + (0..15); lane's q = l15
    const size_t qrow = (size_t)b * L_ + qb*64 + w*16 + l15;
    const uint16_t* qp_ = qkv + qrow * QKVW + h * HD;
    bf16x8 qf[4];
#pragma unroll
    for (int c = 0; c < 4; c++) qf[c] = *(const bf16x8*)(qp_ + c*32 + lh*8);

    float m_s = -3.0e38f, l_s = 0.f;   // per-lane scalars for q = l15
    f32x4 oacc[8];
#pragma unroll
    for (int nt = 0; nt < 8; nt++) oacc[nt] = f32x4{0.f,0.f,0.f,0.f};

    const int ntile = qb + 1;
    ushort8 rk[4], rv[4];

    // prologue: load tile 0 into regs
#pragma unroll
    for (int i = 0; i < 4; i++){
      int g = i*256 + tid, row = g >> 4, c = g & 15;
      rk[i] = *(const ushort8*)(qkv + ((size_t)b*L_ + row)*QKVW + DM + h*HD + c*8);
    }
#pragma unroll
    for (int i = 0; i < 4; i++){
      int g = i*256 + tid, d = g >> 3, c = g & 7;
      rv[i] = *(const ushort8*)(vt + ((size_t)bh*HD + d)*L_ + c*8);
    }

    for (int kt = 0; kt < ntile; kt++){
      __syncthreads();                  // prior tile's LDS reads complete
#pragma unroll
      for (int i = 0; i < 4; i++){ int g = i*256+tid; *(ushort8*)(&Ks[g>>4][(g&15)*8]) = rk[i]; }
#pragma unroll
      for (int i = 0; i < 4; i++){ int g = i*256+tid; *(ushort8*)(&Vs[g>>3][(g&7)*8]) = rv[i]; }
      __syncthreads();

      // T14: issue next tile's global loads now; latency hides under compute
      if (kt + 1 < ntile){
        const int k2 = (kt + 1) * 64;
#pragma unroll
        for (int i = 0; i < 4; i++){
          int g = i*256 + tid, row = g >> 4, c = g & 15;
          rk[i] = *(const ushort8*)(qkv + ((size_t)b*L_ + k2 + row)*QKVW + DM + h*HD + c*8);
        }
#pragma unroll
        for (int i = 0; i < 4; i++){
          int g = i*256 + tid, d = g >> 3, c = g & 7;
          rv[i] = *(const ushort8*)(vt + ((size_t)bh*HD + d)*L_ + k2 + c*8);
        }
      }

      // ---- S^T = K Q^T : s[nt][r] = S[k = nt*16+lh*4+r][q = l15] ----
      f32x4 s[4];
#pragma unroll
      for (int nt = 0; nt < 4; nt++) s[nt] = f32x4{0.f,0.f,0.f,0.f};
      __builtin_amdgcn_s_setprio(1);
#pragma unroll
      for (int c = 0; c < 4; c++){
#pragma unroll
        for (int nt = 0; nt < 4; nt++){
          bf16x8 kf = *(const bf16x8*)(&Ks[nt*16 + l15][c*32 + lh*8]);
          s[nt] = __builtin_amdgcn_mfma_f32_16x16x32_bf16(kf, qf[c], s[nt], 0, 0, 0);
        }
      }
      __builtin_amdgcn_s_setprio(0);

      // ---- scale + causal mask (log2 domain) ----
      const bool diag = (kt == qb);
      const int qg = w*16 + l15;            // q within block
      const int kb = lh*4;                  // k base within each 16-k tile
#pragma unroll
      for (int nt = 0; nt < 4; nt++){
#pragma unroll
        for (int r = 0; r < 4; r++){
          float v = s[nt][r] * SCL;
          if (diag && (nt*16 + kb + r > qg)) v = -1.0e30f;
          s[nt][r] = v;
        }
      }
      // ---- lane-local max over 16 k + 2 cross-lh shuffles ----
      float pm = s[0][0];
#pragma unroll
      for (int nt = 0; nt < 4; nt++)
#pragma unroll
        for (int r = 0; r < 4; r++) pm = fmaxf(pm, s[nt][r]);
      pm = fmaxf(pm, __shfl_xor(pm, 16));
      pm = fmaxf(pm, __shfl_xor(pm, 32));
      // ---- T13 defer-max ----
      if (!__all(pm - m_s <= 8.0f)){
        float mn = fmaxf(m_s, pm);
        float alpha = exp2f(m_s - mn);
        m_s = mn; l_s *= alpha;
        float ar[4];
#pragma unroll
        for (int r = 0; r < 4; r++) ar[r] = __shfl(alpha, lh*4 + r);
#pragma unroll
        for (int nt = 0; nt < 8; nt++)
#pragma unroll
          for (int r = 0; r < 4; r++) oacc[nt][r] *= ar[r];
      }
      // ---- P = exp2(S - m), pack 4 consecutive k, store b64; sum ----
      float rs = 0.f;
#pragma unroll
      for (int nt = 0; nt < 4; nt++){
        float p0 = exp2f(s[nt][0] - m_s);
        float p1 = exp2f(s[nt][1] - m_s);
        float p2 = exp2f(s[nt][2] - m_s);
        float p3 = exp2f(s[nt][3] - m_s);
        rs += (p0 + p1) + (p2 + p3);
        uint2 pk;
        pk.x = (uint32_t)f2bf(p0) | ((uint32_t)f2bf(p1) << 16);
        pk.y = (uint32_t)f2bf(p2) | ((uint32_t)f2bf(p3) << 16);
        *(uint2*)(&Ps[w][l15][nt*16 + kb]) = pk;
      }
      rs += __shfl_xor(rs, 16);
      rs += __shfl_xor(rs, 32);
      l_s += rs;

      asm volatile("s_waitcnt lgkmcnt(0)" ::: "memory");   // Ps writes visible (wave-private)
      // ---- O += P V : A=P[16q][64k] (LDS), B=V[64k][128d] (LDS) ----
      __builtin_amdgcn_s_setprio(1);
#pragma unroll
      for (int kc = 0; kc < 2; kc++){
        bf16x8 pf = *(const bf16x8*)(&Ps[w][l15][kc*32 + lh*8]);
#pragma unroll
        for (int nt = 0; nt < 8; nt++){
          bf16x8 vf = *(const bf16x8*)(&Vs[nt*16 + l15][kc*32 + lh*8]);
          oacc[nt] = __builtin_amdgcn_mfma_f32_16x16x32_bf16(pf, vf, oacc[nt], 0, 0, 0);
        }
      }
      __builtin_amdgcn_s_setprio(0);
    }
    // ---- epilogue: redistribute l to oacc rows, O /= l, write ----
    float invl[4];
#pragma unroll
    for (int r = 0; r < 4; r++) invl[r] = 1.f / __shfl(l_s, lh*4 + r);
#pragma unroll
    for (int nt = 0; nt < 8; nt++){
#pragma unroll
      for (int r = 0; r < 4; r++){
        float v = oacc[nt][r] * invl[r];
        size_t row = (size_t)b*L_ + qb*64 + w*16 + lh*4 + r;
        ao[row * DM + h*HD + nt*16 + l15] = f2bf(v);
      }
    }
  }
}

// ---------------------------------------------------------------------------
extern "C" void kernel_launch(void* const* d_in, const int* in_sizes, int n_in,
                              void* d_out, int out_size, void* d_ws, size_t ws_size,
                              hipStream_t stream)
{
  (void)in_sizes; (void)n_in; (void)out_size; (void)ws_size;
  const float* x       = (const float*)d_in[0];
  const float* w_qkv   = (const float*)d_in[1];
  const float* b_qkv   = (const float*)d_in[2];
  const float* q_scale = (const float*)d_in[3];
  const float* k_scale = (const float*)d_in[4];
  const float* w_out   = (const float*)d_in[5];
  const float* b_out   = (const float*)d_in[6];
  float* out = (float*)d_out;

  // workspace layout (~102 MB), with lifetime-based reuse
  char* ws = (char*)d_ws;
  uint16_t* qkv   = (uint16_t*)(ws);                                   // 50,331,648 B
  uint16_t* reg1  = (uint16_t*)(ws + 50331648);                        // 16,777,216 B
  uint16_t* reg2  = (uint16_t*)(ws + 50331648 + 16777216);             // 25,165,824 B
  uint16_t* woutT = (uint16_t*)(ws + 50331648 + 16777216 + 25165824);  //  8,388,608 B
  float*    ct    = (float*)(ws + 100663296);                          //    524,288 B
  float*    st    = ct + 131072;                                       //    524,288 B

  uint16_t* xb    = reg1;   // x bf16 [4096][2048]   (dead after gemm_qkv)
  uint16_t* ao    = reg1;   // attn out bf16 [4096][2048]
  uint16_t* wqkvT = reg2;   // [6144][2048]          (dead after gemm_qkv)
  uint16_t* vt    = reg2;   // [32][128][2048]

  rope_table  <<<512, 256, 0, stream>>>(ct, st);
  cvt_f32_bf16<<<4096, 256, 0, stream>>>(x, xb, 1048576);
  transpose_w <<<dim3(32, 96), 256, 0, stream>>>(w_qkv, wqkvT, 2048, 6144);
  transpose_w <<<dim3(32, 32), 256, 0, stream>>>(w_out, woutT, 2048, 2048);
  gemm8p<1>   <<<768, 512, 0, stream>>>(xb, wqkvT, b_qkv, qkv, 4096, 6144, 2048, 48);
  rmsrope     <<<4096, 256, 0, stream>>>(qkv, q_scale, k_scale, ct, st);
  transpose_v <<<dim3(32, 32), 256, 0, stream>>>(qkv, vt);
  flash_attn  <<<dim3(16, 32), 256, 0, stream>>>(qkv, vt, ao);
  gemm8p<0>   <<<256, 512, 0, stream>>>(ao, woutT, b_out, out, 4096, 2048, 2048, 16);
}

// Round 10
// 281.523 us; speedup vs baseline: 1.6168x; 1.0483x over previous
//
#include <hip/hip_runtime.h>
#include <hip/hip_bf16.h>
#include <stdint.h>

// ---------------------------------------------------------------------------
// Fused attention block, bf16 MFMA pipeline:
//   cvt(x) / transpose(w_qkv,w_out) -> GEMM qkv (gemm8p, 64x64/wave,
//   single-barrier K-loop) -> rmsnorm+rope -> transpose V -> flash attention
//   (swapped QK^T lane-local softmax, T5, T13) -> GEMM out-proj (+bias, fp32)
// ---------------------------------------------------------------------------

typedef unsigned short ushort8 __attribute__((ext_vector_type(8)));
typedef short          bf16x8 __attribute__((ext_vector_type(8)));
typedef float          f32x4  __attribute__((ext_vector_type(4)));

#define B_   2
#define L_   2048
#define DM   2048
#define NH   16
#define HD   128
#define QKVW 6144   // 3*DM

__device__ __forceinline__ uint16_t f2bf(float f){
  uint32_t u = __builtin_bit_cast(uint32_t, f);
  u += 0x7FFFu + ((u >> 16) & 1u);          // RNE
  return (uint16_t)(u >> 16);
}
__device__ __forceinline__ float bf2f(uint16_t h){
  uint32_t u = ((uint32_t)h) << 16;
  return __builtin_bit_cast(float, u);
}

// async global->LDS, 16B per lane; LDS dest is wave-uniform base + lane*16
#define GLD16(gp, lp) __builtin_amdgcn_global_load_lds( \
  (const __attribute__((address_space(1))) void*)(gp),  \
  (__attribute__((address_space(3))) void*)(lp), 16, 0, 0)

// ---------------- rope cos/sin table: [2048][64] each --------------------
__global__ __launch_bounds__(256) void rope_table(float* __restrict__ ct, float* __restrict__ st){
  int i = blockIdx.x * 256 + threadIdx.x;   // 131072 threads
  int t = i >> 6, d = i & 63;
  float invf = powf(10000.f, -(float)d * (1.f/64.f));
  float s, c;
  sincosf((float)t * invf, &s, &c);
  ct[i] = c; st[i] = s;
}

// ---------------- fp32 -> bf16 convert (x) -------------------------------
__global__ __launch_bounds__(256) void cvt_f32_bf16(const float* __restrict__ x,
                                                    uint16_t* __restrict__ o, int n8){
  int i = blockIdx.x * 256 + threadIdx.x;
  if (i < n8){
    const float4* xv = (const float4*)x;
    float4 a = xv[(size_t)i*2], b = xv[(size_t)i*2+1];
    ushort8 v;
    v[0]=f2bf(a.x); v[1]=f2bf(a.y); v[2]=f2bf(a.z); v[3]=f2bf(a.w);
    v[4]=f2bf(b.x); v[5]=f2bf(b.y); v[6]=f2bf(b.z); v[7]=f2bf(b.w);
    *(ushort8*)(o + (size_t)i*8) = v;
  }
}

// ---------------- W [R][C] fp32 -> Wt [C][R] bf16 ------------------------
__global__ __launch_bounds__(256) void transpose_w(const float* __restrict__ W,
                                                   uint16_t* __restrict__ Wt, int R, int C){
  __shared__ float T[64][65];
  const int rb = blockIdx.x, cb = blockIdx.y;
  const int tid = threadIdx.x;
#pragma unroll
  for (int i=0;i<4;i++){
    int rr = i*16 + (tid >> 4);
    int cc = (tid & 15) * 4;
    float4 v = *(const float4*)(W + (size_t)(rb*64 + rr) * C + cb*64 + cc);
    T[rr][cc] = v.x; T[rr][cc+1] = v.y; T[rr][cc+2] = v.z; T[rr][cc+3] = v.w;
  }
  __syncthreads();
  const int oc = tid >> 2, rc = (tid & 3) * 16;
  ushort8 o0, o1;
#pragma unroll
  for (int j=0;j<8;j++){ o0[j] = f2bf(T[rc+j][oc]); o1[j] = f2bf(T[rc+8+j][oc]); }
  size_t ob = (size_t)(cb*64 + oc) * R + rb*64 + rc;
  *(ushort8*)(Wt + ob)     = o0;
  *(ushort8*)(Wt + ob + 8) = o1;
}

// ---------------- GEMM: C[M][N] = A[M][K] * Bt[N][K]^T + bias ------------
// Single-barrier K-loop: 3-slot LDS ring, prefetch distance 2, counted
// vmcnt(6), T2 XOR-swizzle (0 conflicts), T5 setprio, 8 waves as 4M x 2N
// (64x64/wave, acc[4][4]). NO in-tile barriers: all 16 ds_read issued
// up-front, STAGE follows, MFMAs consume with compiler fine-grained lgkmcnt
// -> waves drift, LDS pipe overlaps matrix pipe (m114).
// Race audit: slot s read at tile t is re-staged at t+1; reader's ds_reads
// are consumed by its own MFMAs BEFORE the boundary barrier, stager writes
// AFTER it (WAR ok). Stage(t)->slot (t+2)%3 drained by vmcnt(6) at boundary
// t+1 before its readers at t+2 (RAW ok).
template<int OUTB>
__global__ __launch_bounds__(512, 2) void gemm8p(
    const uint16_t* __restrict__ A, const uint16_t* __restrict__ Bt,
    const float* __restrict__ bias, void* __restrict__ Cv,
    int M, int N, int K, int nbn)
{
  __shared__ uint16_t LA[3*16384];   // 3 x [256][64]
  __shared__ uint16_t LB[3*8192];    // 3 x [128][64]
  const int nwg = (M >> 8) * nbn;
  const int q8  = nwg >> 3;
  const int id  = ((int)blockIdx.x & 7) * q8 + ((int)blockIdx.x >> 3);
  const int bm = id / nbn, bn = id % nbn;
  const int tid = threadIdx.x;
  const int lane = tid & 63, w = tid >> 6;
  const int wm = w & 3, wn = w >> 2;          // 4M x 2N, 64x64 per wave
  const int l15 = lane & 15, lh = lane >> 4;
  const int NT = K >> 6;

  // staging: per-lane inverse-swizzled global source column
  const int qs3 = ((lane & 7) ^ ((lane >> 3) & 7)) * 8;
  const uint16_t* gA_ = A  + (size_t)((bm << 8) + (w << 5) + (lane >> 3)) * K + qs3;
  const uint16_t* gB_ = Bt + (size_t)((bn << 7) + (w << 4) + (lane >> 3)) * K + qs3;
  uint16_t* lA_ = LA + (w << 11);    // wave-uniform LDS bases
  uint16_t* lB_ = LB + (w << 10);

  // fragment-read swizzled offsets (elements)
  const int sw0 = ((lh       ^ (l15 & 7)) << 3);   // kc=0
  const int sw1 = (((4 | lh) ^ (l15 & 7)) << 3);   // kc=1
  const int aoff = (((wm << 6) + l15) << 6);       // rows wm*64 + mi*16 + l15
  const int boff = (((wn << 6) + l15) << 6);       // rows wn*64 + ni*16 + l15

  f32x4 acc[4][4];
#pragma unroll
  for (int i=0;i<4;i++)
#pragma unroll
    for (int j=0;j<4;j++) acc[i][j] = f32x4{0.f,0.f,0.f,0.f};

  auto STAGE_A = [&](int tt, int s, int i){
    GLD16(gA_ + (size_t)tt*64 + (size_t)(i*8)*K, lA_ + s*16384 + i*512);
  };
  auto STAGE_B = [&](int tt, int s, int i){
    GLD16(gB_ + (size_t)tt*64 + (size_t)(i*8)*K, lB_ + s*8192 + i*512);
  };

  // prologue: stage tiles 0,1; wait tile 0 (6 of 12 outstanding = tile 1)
#pragma unroll
  for (int i=0;i<4;i++) STAGE_A(0, 0, i);
#pragma unroll
  for (int i=0;i<2;i++) STAGE_B(0, 0, i);
#pragma unroll
  for (int i=0;i<4;i++) STAGE_A(1, 1, i);
#pragma unroll
  for (int i=0;i<2;i++) STAGE_B(1, 1, i);
  asm volatile("s_waitcnt vmcnt(6)" ::: "memory");
  __builtin_amdgcn_s_barrier();

  int sl = 0, sl2 = 2;
  for (int t = 0; t < NT; ++t){
    const bool pf = (t + 2 < NT);
    const uint16_t* la = LA + sl*16384;
    const uint16_t* lb = LB + sl*8192;

    // all fragment reads for this tile (both kc) - async, lgkm-counted
    bf16x8 af0[4], bf0[4], af1[4], bf1[4];
#pragma unroll
    for (int mi=0;mi<4;mi++) af0[mi] = *(const bf16x8*)(la + aoff + mi*1024 + sw0);
#pragma unroll
    for (int ni=0;ni<4;ni++) bf0[ni] = *(const bf16x8*)(lb + boff + ni*1024 + sw0);
#pragma unroll
    for (int mi=0;mi<4;mi++) af1[mi] = *(const bf16x8*)(la + aoff + mi*1024 + sw1);
#pragma unroll
    for (int ni=0;ni<4;ni++) bf1[ni] = *(const bf16x8*)(lb + boff + ni*1024 + sw1);
    // next-next tile staging (slot disjoint from all live readers)
    if (pf){
      STAGE_A(t+2, sl2, 0); STAGE_A(t+2, sl2, 1);
      STAGE_A(t+2, sl2, 2); STAGE_A(t+2, sl2, 3);
      STAGE_B(t+2, sl2, 0); STAGE_B(t+2, sl2, 1);
    }
    // 32 MFMAs; compiler inserts fine-grained lgkmcnt before first uses
    __builtin_amdgcn_s_setprio(1);
#pragma unroll
    for (int mi=0;mi<4;mi++)
#pragma unroll
      for (int ni=0;ni<4;ni++)
        acc[mi][ni] = __builtin_amdgcn_mfma_f32_16x16x32_bf16(af0[mi], bf0[ni], acc[mi][ni], 0, 0, 0);
#pragma unroll
    for (int mi=0;mi<4;mi++)
#pragma unroll
      for (int ni=0;ni<4;ni++)
        acc[mi][ni] = __builtin_amdgcn_mfma_f32_16x16x32_bf16(af1[mi], bf1[ni], acc[mi][ni], 0, 0, 0);
    __builtin_amdgcn_s_setprio(0);

    // ---- tile boundary: counted vmcnt + single barrier ----
    if (t < NT-2)       { asm volatile("s_waitcnt vmcnt(6)" ::: "memory"); }
    else if (t == NT-2) { asm volatile("s_waitcnt vmcnt(0)" ::: "memory"); }
    if (t < NT-1) __builtin_amdgcn_s_barrier();
    sl  = (sl  == 2) ? 0 : sl  + 1;
    sl2 = (sl2 == 2) ? 0 : sl2 + 1;
  }

  // ---- epilogue ----
  const int cm = (bm << 8) + (wm << 6);
  const int cn = (bn << 7) + (wn << 6);
#pragma unroll
  for (int ni=0;ni<4;ni++){
    int col = cn + ni*16 + l15;
    float bs = bias[col];
#pragma unroll
    for (int mi=0;mi<4;mi++){
#pragma unroll
      for (int r=0;r<4;r++){
        int rowg = cm + mi*16 + lh*4 + r;        // C/D: col=lane&15, row=(lane>>4)*4+r
        float v = acc[mi][ni][r] + bs;
        if (OUTB) ((uint16_t*)Cv)[(size_t)rowg * N + col] = f2bf(v);
        else      ((float*)Cv)[(size_t)rowg * N + col] = v;
      }
    }
  }
}

// ---------------- RMSNorm + RoPE in place on q,k parts of qkv ------------
__global__ __launch_bounds__(256) void rmsrope(
    uint16_t* __restrict__ qkv, const float* __restrict__ qs, const float* __restrict__ ks,
    const float* __restrict__ ct, const float* __restrict__ st)
{
  const int bx  = blockIdx.x;          // token index b*2048+t
  const int t   = bx & (L_-1);
  const int tid = threadIdx.x;
  const int h   = tid >> 4;
  const int dq  = (tid & 15) * 8;
  const int dd  = dq & 63;
  const bool hi = dq >= 64;
  const size_t base = (size_t)bx * QKVW;
  float cs[8], sn[8];
#pragma unroll
  for (int j=0;j<8;j++){ cs[j] = ct[(size_t)t*64 + dd + j]; sn[j] = st[(size_t)t*64 + dd + j]; }
#pragma unroll
  for (int qk = 0; qk < 2; qk++){
    uint16_t* p = qkv + base + qk*DM + h*HD + dq;
    ushort8 vv = *(const ushort8*)p;
    float x[8]; float ssum = 0.f;
#pragma unroll
    for (int j=0;j<8;j++){ x[j] = bf2f(vv[j]); ssum += x[j]*x[j]; }
    ssum += __shfl_xor(ssum, 1); ssum += __shfl_xor(ssum, 2);
    ssum += __shfl_xor(ssum, 4); ssum += __shfl_xor(ssum, 8);
    const float inv = rsqrtf(ssum * (1.f/128.f) + 1e-6f);
    const float* sc = qk ? ks : qs;
    float y[8];
#pragma unroll
    for (int j=0;j<8;j++) y[j] = x[j] * inv * sc[dq + j];
    float z[8];                       // partner half (d +/- 64) via lane^8
#pragma unroll
    for (int j=0;j<8;j++) z[j] = __shfl_xor(y[j], 8);
    ushort8 o;
#pragma unroll
    for (int j=0;j<8;j++){
      float r = hi ? (z[j]*sn[j] + y[j]*cs[j])
                   : (y[j]*cs[j] - z[j]*sn[j]);
      o[j] = f2bf(r);
    }
    *(ushort8*)p = o;
  }
}

// ---------------- V [b][t][h][d] -> VT [b,h][d][t] -----------------------
__global__ __launch_bounds__(256) void transpose_v(const uint16_t* __restrict__ qkv,
                                                   uint16_t* __restrict__ vt){
  __shared__ uint16_t T[64][136];
  const int tb = blockIdx.x, bh = blockIdx.y;
  const int b = bh >> 4, h = bh & 15;
  const int tid = threadIdx.x;
#pragma unroll
  for (int i=0;i<4;i++){
    int g = i*256 + tid, tt = g >> 4, c = g & 15;
    *(ushort8*)(&T[tt][c*8]) =
      *(const ushort8*)(qkv + ((size_t)b*L_ + tb*64 + tt)*QKVW + 2*DM + h*HD + c*8);
  }
  __syncthreads();
  const int d = tid >> 1, th = tid & 1;
#pragma unroll
  for (int i=0;i<4;i++){
    ushort8 o;
#pragma unroll
    for (int j=0;j<8;j++) o[j] = T[th*32 + i*8 + j][d];
    *(ushort8*)(vt + ((size_t)bh*HD + d)*L_ + tb*64 + th*32 + i*8) = o;
  }
}

// ---------------- flash attention (causal, balanced pairs) ---------------
// grid (qp=16, bh=32); block handles q-tiles {qp, 31-qp}: 33 K-tile iters,
// uniform. KVBLK=64, 4 waves x 16 q-rows. Q in regs; K,V reg-prefetched LDS.
// SWAPPED QK^T (mfma(K,Q)): S layout [k][q] -> lane holds 16 k-vals for ONE
// q (=lane&15): softmax reduce = in-lane chain + 2 shuffles (xor16/32);
// P stores as 4x ds_write_b64. alpha/l redistributed to oacc rows (q=lh*4+r)
// via 4 __shfl on the (T13-rare) rescale path / epilogue only.
__global__ __launch_bounds__(256) void flash_attn(
    const uint16_t* __restrict__ qkv, const uint16_t* __restrict__ vt,
    uint16_t* __restrict__ ao)
{
  const int qp = blockIdx.x;
  const int bh = blockIdx.y;
  const int b = bh >> 4, h = bh & 15;
  const int tid = threadIdx.x;
  const int lane = tid & 63, w = tid >> 6;
  const int l15 = lane & 15, lh = lane >> 4;

  __shared__ uint16_t Ks[64][136];
  __shared__ uint16_t Vs[128][72];
  __shared__ uint16_t Ps[4][16][72];

  const float SCL = 0.12751744f;      // (1/sqrt(128)) * log2(e)

  for (int sel = 0; sel < 2; sel++){
    const int qb = sel ? (31 - qp) : qp;

    // Q fragments: wave w owns q rows qb*64 + w*16 + (0..15); lane's q = l15
    const size_t qrow = (size_t)b * L_ + qb*64 + w*16 + l15;
    const uint16_t* qp_ = qkv + qrow * QKVW + h * HD;
    bf16x8 qf[4];
#pragma unroll
    for (int c = 0; c < 4; c++) qf[c] = *(const bf16x8*)(qp_ + c*32 + lh*8);

    float m_s = -3.0e38f, l_s = 0.f;   // per-lane scalars for q = l15
    f32x4 oacc[8];
#pragma unroll
    for (int nt = 0; nt < 8; nt++) oacc[nt] = f32x4{0.f,0.f,0.f,0.f};

    const int ntile = qb + 1;
    ushort8 rk[4], rv[4];

    // prologue: load tile 0 into regs
#pragma unroll
    for (int i = 0; i < 4; i++){
      int g = i*256 + tid, row = g >> 4, c = g & 15;
      rk[i] = *(const ushort8*)(qkv + ((size_t)b*L_ + row)*QKVW + DM + h*HD + c*8);
    }
#pragma unroll
    for (int i = 0; i < 4; i++){
      int g = i*256 + tid, d = g >> 3, c = g & 7;
      rv[i] = *(const ushort8*)(vt + ((size_t)bh*HD + d)*L_ + c*8);
    }

    for (int kt = 0; kt < ntile; kt++){
      __syncthreads();                  // prior tile's LDS reads complete
#pragma unroll
      for (int i = 0; i < 4; i++){ int g = i*256+tid; *(ushort8*)(&Ks[g>>4][(g&15)*8]) = rk[i]; }
#pragma unroll
      for (int i = 0; i < 4; i++){ int g = i*256+tid; *(ushort8*)(&Vs[g>>3][(g&7)*8]) = rv[i]; }
      __syncthreads();

      // T14: issue next tile's global loads now; latency hides under compute
      if (kt + 1 < ntile){
        const int k2 = (kt + 1) * 64;
#pragma unroll
        for (int i = 0; i < 4; i++){
          int g = i*256 + tid, row = g >> 4, c = g & 15;
          rk[i] = *(const ushort8*)(qkv + ((size_t)b*L_ + k2 + row)*QKVW + DM + h*HD + c*8);
        }
#pragma unroll
        for (int i = 0; i < 4; i++){
          int g = i*256 + tid, d = g >> 3, c = g & 7;
          rv[i] = *(const ushort8*)(vt + ((size_t)bh*HD + d)*L_ + k2 + c*8);
        }
      }

      // ---- S^T = K Q^T : s[nt][r] = S[k = nt*16+lh*4+r][q = l15] ----
      f32x4 s[4];
#pragma unroll
      for (int nt = 0; nt < 4; nt++) s[nt] = f32x4{0.f,0.f,0.f,0.f};
      __builtin_amdgcn_s_setprio(1);
#pragma unroll
      for (int c = 0; c < 4; c++){
#pragma unroll
        for (int nt = 0; nt < 4; nt++){
          bf16x8 kf = *(const bf16x8*)(&Ks[nt*16 + l15][c*32 + lh*8]);
          s[nt] = __builtin_amdgcn_mfma_f32_16x16x32_bf16(kf, qf[c], s[nt], 0, 0, 0);
        }
      }
      __builtin_amdgcn_s_setprio(0);

      // ---- scale + causal mask (log2 domain) ----
      const bool diag = (kt == qb);
      const int qg = w*16 + l15;            // q within block
      const int kb = lh*4;                  // k base within each 16-k tile
#pragma unroll
      for (int nt = 0; nt < 4; nt++){
#pragma unroll
        for (int r = 0; r < 4; r++){
          float v = s[nt][r] * SCL;
          if (diag && (nt*16 + kb + r > qg)) v = -1.0e30f;
          s[nt][r] = v;
        }
      }
      // ---- lane-local max over 16 k + 2 cross-lh shuffles ----
      float pm = s[0][0];
#pragma unroll
      for (int nt = 0; nt < 4; nt++)
#pragma unroll
        for (int r = 0; r < 4; r++) pm = fmaxf(pm, s[nt][r]);
      pm = fmaxf(pm, __shfl_xor(pm, 16));
      pm = fmaxf(pm, __shfl_xor(pm, 32));
      // ---- T13 defer-max ----
      if (!__all(pm - m_s <= 8.0f)){
        float mn = fmaxf(m_s, pm);
        float alpha = exp2f(m_s - mn);
        m_s = mn; l_s *= alpha;
        float ar[4];
#pragma unroll
        for (int r = 0; r < 4; r++) ar[r] = __shfl(alpha, lh*4 + r);
#pragma unroll
        for (int nt = 0; nt < 8; nt++)
#pragma unroll
          for (int r = 0; r < 4; r++) oacc[nt][r] *= ar[r];
      }
      // ---- P = exp2(S - m), pack 4 consecutive k, store b64; sum ----
      float rs = 0.f;
#pragma unroll
      for (int nt = 0; nt < 4; nt++){
        float p0 = exp2f(s[nt][0] - m_s);
        float p1 = exp2f(s[nt][1] - m_s);
        float p2 = exp2f(s[nt][2] - m_s);
        float p3 = exp2f(s[nt][3] - m_s);
        rs += (p0 + p1) + (p2 + p3);
        uint2 pk;
        pk.x = (uint32_t)f2bf(p0) | ((uint32_t)f2bf(p1) << 16);
        pk.y = (uint32_t)f2bf(p2) | ((uint32_t)f2bf(p3) << 16);
        *(uint2*)(&Ps[w][l15][nt*16 + kb]) = pk;
      }
      rs += __shfl_xor(rs, 16);
      rs += __shfl_xor(rs, 32);
      l_s += rs;

      asm volatile("s_waitcnt lgkmcnt(0)" ::: "memory");   // Ps writes visible (wave-private)
      // ---- O += P V : A=P[16q][64k] (LDS), B=V[64k][128d] (LDS) ----
      __builtin_amdgcn_s_setprio(1);
#pragma unroll
      for (int kc = 0; kc < 2; kc++){
        bf16x8 pf = *(const bf16x8*)(&Ps[w][l15][kc*32 + lh*8]);
#pragma unroll
        for (int nt = 0; nt < 8; nt++){
          bf16x8 vf = *(const bf16x8*)(&Vs[nt*16 + l15][kc*32 + lh*8]);
          oacc[nt] = __builtin_amdgcn_mfma_f32_16x16x32_bf16(pf, vf, oacc[nt], 0, 0, 0);
        }
      }
      __builtin_amdgcn_s_setprio(0);
    }
    // ---- epilogue: redistribute l to oacc rows, O /= l, write ----
    float invl[4];
#pragma unroll
    for (int r = 0; r < 4; r++) invl[r] = 1.f / __shfl(l_s, lh*4 + r);
#pragma unroll
    for (int nt = 0; nt < 8; nt++){
#pragma unroll
      for (int r = 0; r < 4; r++){
        float v = oacc[nt][r] * invl[r];
        size_t row = (size_t)b*L_ + qb*64 + w*16 + lh*4 + r;
        ao[row * DM + h*HD + nt*16 + l15] = f2bf(v);
      }
    }
  }
}

// ---------------------------------------------------------------------------
extern "C" void kernel_launch(void* const* d_in, const int* in_sizes, int n_in,
                              void* d_out, int out_size, void* d_ws, size_t ws_size,
                              hipStream_t stream)
{
  (void)in_sizes; (void)n_in; (void)out_size; (void)ws_size;
  const float* x       = (const float*)d_in[0];
  const float* w_qkv   = (const float*)d_in[1];
  const float* b_qkv   = (const float*)d_in[2];
  const float* q_scale = (const float*)d_in[3];
  const float* k_scale = (const float*)d_in[4];
  const float* w_out   = (const float*)d_in[5];
  const float* b_out   = (const float*)d_in[6];
  float* out = (float*)d_out;

  // workspace layout (~102 MB), with lifetime-based reuse
  char* ws = (char*)d_ws;
  uint16_t* qkv   = (uint16_t*)(ws);                                   // 50,331,648 B
  uint16_t* reg1  = (uint16_t*)(ws + 50331648);                        // 16,777,216 B
  uint16_t* reg2  = (uint16_t*)(ws + 50331648 + 16777216);             // 25,165,824 B
  uint16_t* woutT = (uint16_t*)(ws + 50331648 + 16777216 + 25165824);  //  8,388,608 B
  float*    ct    = (float*)(ws + 100663296);                          //    524,288 B
  float*    st    = ct + 131072;                                       //    524,288 B

  uint16_t* xb    = reg1;   // x bf16 [4096][2048]   (dead after gemm_qkv)
  uint16_t* ao    = reg1;   // attn out bf16 [4096][2048]
  uint16_t* wqkvT = reg2;   // [6144][2048]          (dead after gemm_qkv)
  uint16_t* vt    = reg2;   // [32][128][2048]

  rope_table  <<<512, 256, 0, stream>>>(ct, st);
  cvt_f32_bf16<<<4096, 256, 0, stream>>>(x, xb, 1048576);
  transpose_w <<<dim3(32, 96), 256, 0, stream>>>(w_qkv, wqkvT, 2048, 6144);
  transpose_w <<<dim3(32, 32), 256, 0, stream>>>(w_out, woutT, 2048, 2048);
  gemm8p<1>   <<<768, 512, 0, stream>>>(xb, wqkvT, b_qkv, qkv, 4096, 6144, 2048, 48);
  rmsrope     <<<4096, 256, 0, stream>>>(qkv, q_scale, k_scale, ct, st);
  transpose_v <<<dim3(32, 32), 256, 0, stream>>>(qkv, vt);
  flash_attn  <<<dim3(16, 32), 256, 0, stream>>>(qkv, vt, ao);
  gemm8p<0>   <<<256, 512, 0, stream>>>(ao, woutT, b_out, out, 4096, 2048, 2048, 16);
}